// Round 7
// baseline (702.517 us; speedup 1.0000x reference)
//
#include <hip/hip_runtime.h>
#include <math.h>

// Problem constants
#define NN      65536
#define GG      64
#define NPG     1024
#define KEIG    32
#define NBUN    64
#define BDIM    4
#define CH      256        // IN_CH == GNN_DIM == NB*BD
#define NBP     384
#define NEDGE   524288

using f16x8 = __attribute__((ext_vector_type(8))) _Float16;
using f16x4 = __attribute__((ext_vector_type(4))) _Float16;
using f32x4 = __attribute__((ext_vector_type(4))) float;

__device__ __forceinline__ float gelu_f(float x) {
    return 0.5f * x * (1.0f + erff(x * 0.70710678118654752440f));
}

// ---------------------------------------------------------------------------
// fp16 MFMA GEMM. Proven through R6: all-coalesced loads (R5, 106->72us) +
// coalesced C16 epilogue (R6, WRITE 80->33MB, 72->62us). R6 counters: occ 19%
// (64KB LDS -> 2 blocks/CU), MfmaUtil 10%, VALU 33%, 57% stall; VGPR=88 shows
// compiler sank the "4-deep" B prefetch to ~2 -> per-wave ILP can't be forced;
// occupancy is the honest latency-hiding lever (R2: 42% occ -> 2.9TB/s).
// R7:
//  - SPLIT-K staging: stage 32KB half-panel (A1), 8 K-steps, barrier, restage
//    A2 into the SAME buffer, 8 more steps. LDS 64->~34KB -> 4 blocks/CU.
//    __launch_bounds__(256,4) caps VGPR at 128 (R6 used 88).
//  - Coalesced RESA residual: moved into the coalesced row-write phase
//    (8 lane-contiguous f16x8 loads, issued before gelu/scatter so HBM/L3
//    latency hides under VALU; packed fp16 add). Kills the 64 scattered
//    2-byte loads/thread that sat behind a vmcnt wait.
//  - B pre-packed fragment-order (R5), 4-named-set rolling prefetch.
// DUAL: A = concat_k(A1, A2), KTOT=512.  RESA: + A1[m,n] residual (NOUT==256).
// WF: fp32 out (direct stores: 16 lanes x 4B = full 64B lines already).
// W16: fp16 out via LDS-staged coalesced rows.
// Outputs disjoint from ALL inputs (graph-replay safety).
// ---------------------------------------------------------------------------
template<int NOUT, int KTOT, bool DUAL, bool ACT, bool RESA, bool WF, bool W16>
__global__ __launch_bounds__(NOUT, (NOUT == 256) ? 4 : 3) void mgemm_k(
    const _Float16* __restrict__ A1, const _Float16* __restrict__ A2,
    const _Float16* __restrict__ Bp, const float* __restrict__ bias,
    float* __restrict__ Cf, _Float16* __restrict__ C16)
{
    constexpr int NT   = KTOT / 32;     // total K-steps (8 or 16)
    constexpr int HALVES = KTOT / 256;  // 1 or 2 half-panels of K=256
    constexpr int ROWB = 512;           // LDS bytes per A row (K=256 half)
    constexpr int CPR  = 32;            // 16B chunks per A row (half)
    constexpr int TOTC = 64 * CPR;      // 2048 chunks per half-panel
    constexpr int NSTG = TOTC / NOUT;   // full stage iters per thread
    constexpr int CTS  = NOUT + 8;      // padded C-tile row stride (halfs)
    constexpr int AH   = 64 * 256;      // A half-panel halfs (32 KB)
    constexpr int CTH  = 64 * CTS;
    constexpr int LDSH = (W16 && CTH > AH) ? CTH : AH;
    __shared__ _Float16 Alds[LDSH];

    const int tid  = threadIdx.x;
    const int lane = tid & 63;
    const int wave = tid >> 6;          // wave owns cols wave*64..wave*64+63
    const int m0   = blockIdx.x * 64;   // block's 64 A rows

    const int r16 = lane & 15;          // fragment row / col within 16
    const int kc  = lane >> 4;          // k-chunk 0..3

    // B packed: chunk((wn*NT + t)*4 + q), lane-contiguous 16B each
    const _Float16* bpp = Bp + ((size_t)wave * NT * 2048) + lane * 8;

    f16x8 pa0, pa1, pa2, pa3, pb0, pb1, pb2, pb3;
    f16x8 pc0, pc1, pc2, pc3, pd0, pd1, pd2, pd3;

#define LDB(P0, P1, P2, P3, T)                                                 \
    {                                                                          \
        const _Float16* bq_ = bpp + (size_t)(T) * 2048;                        \
        P0 = *(const f16x8*)(bq_);                                             \
        P1 = *(const f16x8*)(bq_ + 512);                                       \
        P2 = *(const f16x8*)(bq_ + 1024);                                      \
        P3 = *(const f16x8*)(bq_ + 1536);                                      \
    }

    // stage one 64x256 half-panel (coalesced loads -> regs -> swizzled LDS)
#define STAGE(BASE)                                                            \
    {                                                                          \
        f16x8 stg[NSTG];                                                       \
        _Pragma("unroll")                                                      \
        for (int j = 0; j < NSTG; j++) {                                       \
            const int idx = tid + j * NOUT;                                    \
            const int r = idx >> 5, c = idx & 31;                              \
            stg[j] = *(const f16x8*)((BASE) + (size_t)(m0 + r) * 256 + c * 8); \
        }                                                                      \
        _Pragma("unroll")                                                      \
        for (int j = 0; j < NSTG; j++) {                                       \
            const int idx = tid + j * NOUT;                                    \
            const int r = idx >> 5, c = idx & 31;                              \
            *(f16x8*)((char*)Alds + ((r * ROWB + c * 16) ^ ((r & 7) << 4))) = stg[j]; \
        }                                                                      \
        if (TOTC % NOUT) {                                                     \
            const int idx = tid + NSTG * NOUT;                                 \
            if (idx < TOTC) {                                                  \
                const int r = idx >> 5, c = idx & 31;                          \
                f16x8 v = *(const f16x8*)((BASE) + (size_t)(m0 + r) * 256 + c * 8); \
                *(f16x8*)((char*)Alds + ((r * ROWB + c * 16) ^ ((r & 7) << 4))) = v; \
            }                                                                  \
        }                                                                      \
    }

    // issue B prefetch for steps 0..3 BEFORE staging (overlaps A latency)
    LDB(pa0, pa1, pa2, pa3, 0)
    LDB(pb0, pb1, pb2, pb3, 1)
    LDB(pc0, pc1, pc2, pc3, 2)
    LDB(pd0, pd1, pd2, pd3, 3)

    STAGE(A1)
    __syncthreads();

    f32x4 acc[4][4];
#pragma unroll
    for (int i = 0; i < 4; i++)
#pragma unroll
        for (int j = 0; j < 4; j++) acc[i][j] = 0.f;

#define MSTEP(OFF, P0, P1, P2, P3)                                             \
    {                                                                          \
        const char* ap_ = (const char*)Alds + (OFF);                           \
        f16x8 a0_ = *(const f16x8*)(ap_);                                      \
        f16x8 a1_ = *(const f16x8*)(ap_ + 16 * ROWB);                          \
        f16x8 a2_ = *(const f16x8*)(ap_ + 32 * ROWB);                          \
        f16x8 a3_ = *(const f16x8*)(ap_ + 48 * ROWB);                          \
        acc[0][0] = __builtin_amdgcn_mfma_f32_16x16x32_f16(a0_, P0, acc[0][0], 0, 0, 0); \
        acc[0][1] = __builtin_amdgcn_mfma_f32_16x16x32_f16(a0_, P1, acc[0][1], 0, 0, 0); \
        acc[0][2] = __builtin_amdgcn_mfma_f32_16x16x32_f16(a0_, P2, acc[0][2], 0, 0, 0); \
        acc[0][3] = __builtin_amdgcn_mfma_f32_16x16x32_f16(a0_, P3, acc[0][3], 0, 0, 0); \
        acc[1][0] = __builtin_amdgcn_mfma_f32_16x16x32_f16(a1_, P0, acc[1][0], 0, 0, 0); \
        acc[1][1] = __builtin_amdgcn_mfma_f32_16x16x32_f16(a1_, P1, acc[1][1], 0, 0, 0); \
        acc[1][2] = __builtin_amdgcn_mfma_f32_16x16x32_f16(a1_, P2, acc[1][2], 0, 0, 0); \
        acc[1][3] = __builtin_amdgcn_mfma_f32_16x16x32_f16(a1_, P3, acc[1][3], 0, 0, 0); \
        acc[2][0] = __builtin_amdgcn_mfma_f32_16x16x32_f16(a2_, P0, acc[2][0], 0, 0, 0); \
        acc[2][1] = __builtin_amdgcn_mfma_f32_16x16x32_f16(a2_, P1, acc[2][1], 0, 0, 0); \
        acc[2][2] = __builtin_amdgcn_mfma_f32_16x16x32_f16(a2_, P2, acc[2][2], 0, 0, 0); \
        acc[2][3] = __builtin_amdgcn_mfma_f32_16x16x32_f16(a2_, P3, acc[2][3], 0, 0, 0); \
        acc[3][0] = __builtin_amdgcn_mfma_f32_16x16x32_f16(a3_, P0, acc[3][0], 0, 0, 0); \
        acc[3][1] = __builtin_amdgcn_mfma_f32_16x16x32_f16(a3_, P1, acc[3][1], 0, 0, 0); \
        acc[3][2] = __builtin_amdgcn_mfma_f32_16x16x32_f16(a3_, P2, acc[3][2], 0, 0, 0); \
        acc[3][3] = __builtin_amdgcn_mfma_f32_16x16x32_f16(a3_, P3, acc[3][3], 0, 0, 0); \
    }

    const int swz = (r16 & 7) << 4;
#pragma unroll
    for (int h = 0; h < HALVES; ++h) {
        if (h > 0) {
            __syncthreads();            // all waves done reading half 0
            STAGE(A2)
            __syncthreads();
        }
        int au = r16 * ROWB + kc * 16;
#pragma unroll
        for (int tt = 0; tt < 8; tt += 4) {
            const int t = h * 8 + tt;   // global K-step for B indexing
            MSTEP((au      ) ^ swz, pa0, pa1, pa2, pa3)
            if (t + 4 < NT) LDB(pa0, pa1, pa2, pa3, t + 4)
            MSTEP((au +  64) ^ swz, pb0, pb1, pb2, pb3)
            if (t + 5 < NT) LDB(pb0, pb1, pb2, pb3, t + 5)
            MSTEP((au + 128) ^ swz, pc0, pc1, pc2, pc3)
            if (t + 6 < NT) LDB(pc0, pc1, pc2, pc3, t + 6)
            MSTEP((au + 192) ^ swz, pd0, pd1, pd2, pd3)
            if (t + 7 < NT) LDB(pd0, pd1, pd2, pd3, t + 7)
            au += 256;
        }
    }
#undef LDB
#undef MSTEP
#undef STAGE

    // epilogue: C[m = quad*4+reg][n = lane&15] per 16x16 tile (m89 layout)
    const int rbase = (lane >> 4) * 4;
    const int ncol  = lane & 15;
    if constexpr (W16) {
        __syncthreads();                // all waves done reading Alds
        constexpr int CPRN = NOUT / 8;  // 16B chunks per C row
        constexpr int CPT  = 64 * CPRN / NOUT;   // chunks per thread (= 8)
        // issue coalesced residual loads early (hide under gelu VALU work)
        f16x8 res[CPT];
        if constexpr (RESA) {
#pragma unroll
            for (int k2 = 0; k2 < CPT; k2++) {
                const int c = tid + k2 * NOUT;
                const int row = c / CPRN, col = c - row * CPRN;
                res[k2] = *(const f16x8*)(A1 + (size_t)(m0 + row) * 256 + col * 8);
            }
        }
        // scatter bias+act into padded LDS C-tile
#pragma unroll
        for (int nt = 0; nt < 4; nt++) {
            const int n = wave * 64 + nt * 16 + ncol;
            const float bs = bias[n];
#pragma unroll
            for (int mt = 0; mt < 4; mt++) {
#pragma unroll
                for (int i = 0; i < 4; i++) {
                    const int mr = mt * 16 + rbase + i;
                    float v = acc[mt][nt][i] + bs;
                    if (ACT) v = gelu_f(v);
                    Alds[mr * CTS + n] = (_Float16)v;
                }
            }
        }
        __syncthreads();
        // coalesced row-write (+ packed fp16 residual add)
#pragma unroll
        for (int k2 = 0; k2 < CPT; k2++) {
            const int c = tid + k2 * NOUT;
            const int row = c / CPRN, col = c - row * CPRN;
            f16x8 v = *(const f16x8*)&Alds[row * CTS + col * 8];
            if constexpr (RESA) v = v + res[k2];
            *(f16x8*)(C16 + (size_t)(m0 + row) * NOUT + col * 8) = v;
        }
    } else {
#pragma unroll
        for (int nt = 0; nt < 4; nt++) {
            const int n = wave * 64 + nt * 16 + ncol;
            const float bs = bias[n];
#pragma unroll
            for (int mt = 0; mt < 4; mt++) {
#pragma unroll
                for (int i = 0; i < 4; i++) {
                    const int m = m0 + mt * 16 + rbase + i;
                    float v = acc[mt][nt][i] + bs;
                    if (ACT) v = gelu_f(v);
                    if (RESA) v += (float)A1[(size_t)m * 256 + n];
                    if (WF) Cf[(size_t)m * NOUT + n] = v;
                }
            }
        }
    }
}

// ---------------------------------------------------------------------------
// Weight pack: fp32 W[k][n] (k-major, row stride NOUT) -> fragment-ordered
// fp16 chunks. Chunk cid = ((wn*NT + t)*4 + q)*64 + l holds 8 halfs:
// value[j] = W[t*32 + (l>>4)*8 + j][wn*64 + q*16 + (l&15)].
// DUAL: k >= 256 reads W2[k-256][n].
// ---------------------------------------------------------------------------
template<int NOUT, int KTOT, bool DUAL>
__global__ __launch_bounds__(256) void pack_k(
    const float* __restrict__ W1, const float* __restrict__ W2,
    _Float16* __restrict__ Bp)
{
    constexpr int NT = KTOT / 32;
    const int cid = blockIdx.x * 256 + threadIdx.x;
    if (cid >= NOUT * KTOT / 8) return;
    const int l  = cid & 63;
    const int q  = (cid >> 6) & 3;
    const int c2 = cid >> 8;            // wn*NT + t
    const int t  = c2 & (NT - 1);
    const int wn = c2 / NT;
    const int n  = wn * 64 + q * 16 + (l & 15);
    const int k0 = t * 32 + (l >> 4) * 8;
    f16x8 v;
#pragma unroll
    for (int j = 0; j < 8; j++) {
        const int k = k0 + j;
        float w = (DUAL && k >= 256) ? W2[(size_t)(k - 256) * NOUT + n]
                                     : W1[(size_t)k * NOUT + n];
        v[j] = (_Float16)w;
    }
    *(f16x8*)(Bp + (size_t)cid * 8) = v;
}

// ---------------------------------------------------------------------------
__global__ void zero_k(float* __restrict__ p, size_t n)
{
    size_t i = (size_t)blockIdx.x * blockDim.x + threadIdx.x;
    float4* p4 = (float4*)p;
    size_t n4 = n >> 2;
    for (size_t j = i; j < n4; j += (size_t)gridDim.x * blockDim.x)
        p4[j] = make_float4(0.f, 0.f, 0.f, 0.f);
}

// fp32 -> fp16 convert (4 elems/thread)
__global__ __launch_bounds__(256) void cvt16_k(
    const float* __restrict__ in, _Float16* __restrict__ out)
{
    size_t i = (size_t)blockIdx.x * 256 + threadIdx.x;
    float4 v = ((const float4*)in)[i];
    f16x4 o = { (_Float16)v.x, (_Float16)v.y, (_Float16)v.z, (_Float16)v.w };
    ((f16x4*)out)[i] = o;
}

__global__ void bcomb_k(const float* __restrict__ a, const float* __restrict__ b,
                        float* __restrict__ o)
{
    int i = blockIdx.x * 256 + threadIdx.x;
    if (i < 512) o[i] = a[i] + b[i];
}

// ---------------------------------------------------------------------------
// CSR build: histogram of dst, exclusive scan, cursor fill
// ---------------------------------------------------------------------------
__global__ __launch_bounds__(256) void hist_k(const int* __restrict__ ei, int* __restrict__ deg)
{
    int e = blockIdx.x * 256 + threadIdx.x;
    if (e < NEDGE) atomicAdd(&deg[ei[NEDGE + e]], 1);
}

__global__ __launch_bounds__(1024) void scan_k(
    const int* __restrict__ deg, int* __restrict__ off, int* __restrict__ cursor)
{
    __shared__ int sh[1024];
    const int tid = threadIdx.x;
    const int base = tid * 64;
    int s = 0;
#pragma unroll 8
    for (int i = 0; i < 64; i++) s += deg[base + i];
    const int mysum = s;
    sh[tid] = s;
    __syncthreads();
    for (int ofs = 1; ofs < 1024; ofs <<= 1) {
        int v = (tid >= ofs) ? sh[tid - ofs] : 0;
        __syncthreads();
        sh[tid] += v;
        __syncthreads();
    }
    int running = sh[tid] - mysum;
    for (int i = 0; i < 64; i++) {
        off[base + i] = running;
        cursor[base + i] = running;
        running += deg[base + i];
    }
    if (tid == 1023) off[NN] = running;
}

__global__ __launch_bounds__(256) void fill_k(
    const int* __restrict__ ei, int* __restrict__ cursor, int* __restrict__ csr)
{
    int e = blockIdx.x * 256 + threadIdx.x;
    if (e < NEDGE) {
        int d = ei[NEDGE + e];
        int pos = atomicAdd(&cursor[d], 1);
        csr[pos] = ei[e];   // src
    }
}

// ---------------------------------------------------------------------------
// Gather segment-sum over fp16 h: fp32 accum, fp16 out. 4 rows in flight.
// ---------------------------------------------------------------------------
__global__ __launch_bounds__(256) void gather16_k(
    const _Float16* __restrict__ h, const int* __restrict__ off,
    const int* __restrict__ csr, _Float16* __restrict__ agg)
{
    const int lane = threadIdx.x & 63;
    const int n = blockIdx.x * 4 + (threadIdx.x >> 6);
    const int s0 = off[n], s1 = off[n + 1];
    float a0 = 0.f, a1 = 0.f, a2 = 0.f, a3 = 0.f;
    int j = s0;
    for (; j + 3 < s1; j += 4) {
        const int i0 = csr[j], i1 = csr[j + 1], i2 = csr[j + 2], i3 = csr[j + 3];
        f16x4 v0 = ((const f16x4*)(h + (size_t)i0 * CH))[lane];
        f16x4 v1 = ((const f16x4*)(h + (size_t)i1 * CH))[lane];
        f16x4 v2 = ((const f16x4*)(h + (size_t)i2 * CH))[lane];
        f16x4 v3 = ((const f16x4*)(h + (size_t)i3 * CH))[lane];
        a0 += (float)v0[0] + (float)v1[0] + (float)v2[0] + (float)v3[0];
        a1 += (float)v0[1] + (float)v1[1] + (float)v2[1] + (float)v3[1];
        a2 += (float)v0[2] + (float)v1[2] + (float)v2[2] + (float)v3[2];
        a3 += (float)v0[3] + (float)v1[3] + (float)v2[3] + (float)v3[3];
    }
    for (; j < s1; j++) {
        f16x4 va = ((const f16x4*)(h + (size_t)csr[j] * CH))[lane];
        a0 += (float)va[0]; a1 += (float)va[1]; a2 += (float)va[2]; a3 += (float)va[3];
    }
    f16x4 o = { (_Float16)a0, (_Float16)a1, (_Float16)a2, (_Float16)a3 };
    ((f16x4*)(agg + (size_t)n * CH))[lane] = o;
}

// ---------------------------------------------------------------------------
// Householder Q from 6 fp16 params (BD=4: 3 reflectors)
// ---------------------------------------------------------------------------
__device__ __forceinline__ void make_Q(const _Float16* __restrict__ p, float Q[4][4])
{
#pragma unroll
    for (int i = 0; i < 4; i++)
#pragma unroll
        for (int j = 0; j < 4; j++) Q[i][j] = (i == j) ? 1.f : 0.f;
    int idx = 0;
#pragma unroll
    for (int j = 0; j < 3; j++) {
        float v[4] = {0.f, 0.f, 0.f, 0.f};
        v[j] = 1.f;
#pragma unroll
        for (int t = 0; t < 4; t++)
            if (t > j) v[t] = (float)p[idx + t - (j + 1)];
        idx += 3 - j;
        float nrm = v[0]*v[0] + v[1]*v[1] + v[2]*v[2] + v[3]*v[3];
        float s = 2.f / nrm;
#pragma unroll
        for (int i = 0; i < 4; i++) {
            float qv = Q[i][0]*v[0] + Q[i][1]*v[1] + Q[i][2]*v[2] + Q[i][3]*v[3];
            float t0 = s * qv;
#pragma unroll
            for (int c = 0; c < 4; c++) Q[i][c] -= t0 * v[c];
        }
    }
}

// Bundle transform: block = 4 nodes x 64 bundles; node_rep is fp16
template<bool TRANS>
__global__ __launch_bounds__(256) void bundle_k(
    const float* __restrict__ vin, const _Float16* __restrict__ nr,
    float* __restrict__ out)
{
    __shared__ _Float16 pb[4 * NBP];
    const int n0 = blockIdx.x * 4;
    for (int i = threadIdx.x; i < 4 * NBP; i += 256)
        pb[i] = nr[(size_t)n0 * NBP + i];
    __syncthreads();
    const int ln = threadIdx.x >> 6;
    const int b  = threadIdx.x & 63;
    const int n  = n0 + ln;
    float Q[4][4];
    make_Q(&pb[ln * NBP + b * 6], Q);
    float4 xv = ((const float4*)(vin + (size_t)n * CH))[b];
    float in0 = xv.x, in1 = xv.y, in2 = xv.z, in3 = xv.w;
    float4 o;
    if constexpr (!TRANS) {
        o.x = Q[0][0]*in0 + Q[0][1]*in1 + Q[0][2]*in2 + Q[0][3]*in3;
        o.y = Q[1][0]*in0 + Q[1][1]*in1 + Q[1][2]*in2 + Q[1][3]*in3;
        o.z = Q[2][0]*in0 + Q[2][1]*in1 + Q[2][2]*in2 + Q[2][3]*in3;
        o.w = Q[3][0]*in0 + Q[3][1]*in1 + Q[3][2]*in2 + Q[3][3]*in3;
    } else {
        o.x = Q[0][0]*in0 + Q[1][0]*in1 + Q[2][0]*in2 + Q[3][0]*in3;
        o.y = Q[0][1]*in0 + Q[1][1]*in1 + Q[2][1]*in2 + Q[3][1]*in3;
        o.z = Q[0][2]*in0 + Q[1][2]*in1 + Q[2][2]*in2 + Q[3][2]*in3;
        o.w = Q[0][3]*in0 + Q[1][3]*in1 + Q[2][3]*in2 + Q[3][3]*in3;
    }
    ((float4*)(out + (size_t)n * CH))[b] = o;
}

// ---------------------------------------------------------------------------
// Spectral kernels
// ---------------------------------------------------------------------------
__global__ __launch_bounds__(256) void spec_proj_k(
    const float* __restrict__ v, const float* __restrict__ eigvec, float* __restrict__ hs)
{
    const int g = blockIdx.x;
    const int nbase = g * NPG + blockIdx.y * 128;
    __shared__ float evs[16][32];
    float acc[32];
#pragma unroll
    for (int k = 0; k < 32; k++) acc[k] = 0.f;
    for (int nt = 0; nt < 128; nt += 16) {
        __syncthreads();
        for (int i = threadIdx.x; i < 512; i += 256) {
            int nn = i >> 5, kk = i & 31;
            evs[nn][kk] = eigvec[(size_t)(nbase + nt + nn) * KEIG + kk];
        }
        __syncthreads();
#pragma unroll 4
        for (int nn = 0; nn < 16; nn++) {
            float hv = v[(size_t)(nbase + nt + nn) * CH + threadIdx.x];
#pragma unroll
            for (int k = 0; k < 32; k++) acc[k] += evs[nn][k] * hv;
        }
    }
    float* o = hs + (size_t)g * KEIG * CH + threadIdx.x;
#pragma unroll
    for (int k = 0; k < 32; k++) atomicAdd(o + k * CH, acc[k]);
}

// out16[g,n,d] = sum_v ev[g,n,v] * hs[g,v,d] * exp(-eigval[g,v]*taus[d>>2])
// (spec_scale fused into the hs load)
__global__ __launch_bounds__(256) void spec_reproj16_k(
    const float* __restrict__ eigvec, const float* __restrict__ hs,
    const float* __restrict__ eigval, const float* __restrict__ taus,
    _Float16* __restrict__ out16)
{
    const int g = blockIdx.x >> 4;
    const int nbase = g * NPG + (blockIdx.x & 15) * 64;
    const float tau = taus[threadIdx.x >> 2];
    float hsr[32];
    const float* hg = hs + (size_t)g * KEIG * CH + threadIdx.x;
#pragma unroll
    for (int k = 0; k < 32; k++)
        hsr[k] = hg[k * CH] * expf(-eigval[g * KEIG + k] * tau);
    __shared__ float evs[64][32];
    for (int i = threadIdx.x; i < 2048; i += 256) {
        int nn = i >> 5, kk = i & 31;
        evs[nn][kk] = eigvec[(size_t)(nbase + nn) * KEIG + kk];
    }
    __syncthreads();
    for (int nn = 0; nn < 64; nn++) {
        float a = 0.f;
#pragma unroll
        for (int k = 0; k < 32; k++) a += evs[nn][k] * hsr[k];
        out16[(size_t)(nbase + nn) * CH + threadIdx.x] = (_Float16)a;
    }
}

// ---------------------------------------------------------------------------
extern "C" void kernel_launch(void* const* d_in, const int* in_sizes, int n_in,
                              void* d_out, int out_size, void* d_ws, size_t ws_size,
                              hipStream_t stream)
{
    const float* x      = (const float*)d_in[0];
    const float* eigvec = (const float*)d_in[1];
    const float* eigval = (const float*)d_in[2];
    const float* taus   = (const float*)d_in[3];
    const float* enc_w  = (const float*)d_in[4];
    const float* enc_b  = (const float*)d_in[5];
    const float* self_w = (const float*)d_in[6];
    const float* self_b = (const float*)d_in[7];
    const float* nb_w   = (const float*)d_in[8];
    const float* nb_b   = (const float*)d_in[9];
    const float* dec_w  = (const float*)d_in[10];
    const float* dec_b  = (const float*)d_in[11];
    const float* lin_w  = (const float*)d_in[12];
    const float* lin_b  = (const float*)d_in[13];
    const int*   ei     = (const int*)d_in[14];
    (void)in_sizes; (void)n_in; (void)out_size; (void)ws_size;

    float* ws = (float*)d_ws;
    // Stream-ordered lifetimes (float-slot offsets):
    //  [0,        8388608)  x16          -> vf1[0:half] / h3
    //  [8388608, 16777216)  h0           -> vf1[half:]  / h3
    //  [16777216,25165824)  h1           -> hs (@16.7M) ; free tail
    //  [25165824,33554432)  agg          -> nr16 part
    //  [33554432,34275329)  CSR ints     -> nr16 part
    //  [25165824,37748736)  nr16 [NN,384] fp16 (dec out; agg+CSR dead)
    //  [37748752,37995024)  packed weights + lbias
    //  [37995024,46383632)  h2 [NN,256] fp16
    // high-water: 46,383,632 fl = 185.5 MB
    _Float16* x16 = (_Float16*)(ws);
    _Float16* h0  = (_Float16*)(ws + 8388608);
    _Float16* h1  = (_Float16*)(ws + 16777216);
    _Float16* agg = (_Float16*)(ws + 25165824);
    int* ibase  = (int*)(ws + 33554432);
    int* deg    = ibase;                 // NN
    int* off    = ibase + 65536;         // NN+1
    int* cursor = ibase + 131073;        // NN
    int* csr    = ibase + 196609;        // NEDGE (ends slot 34275329)
    _Float16* nr16 = (_Float16*)(ws + 25165824);  // [NN,384] fp16
    float* wb = ws + 37748752;
    _Float16* enc16 = (_Float16*)(wb);            // packed [256x256]
    _Float16* l1w   = (_Float16*)(wb + 32768);    // packed [256x512]
    _Float16* l2w   = (_Float16*)(wb + 98304);    // packed [256x512]
    _Float16* dec16 = (_Float16*)(wb + 163840);   // packed [384x256]
    _Float16* lin16 = (_Float16*)(wb + 212992);   // packed [256x256]
    float* lbias = wb + 245760;                   // [2,256] (ends wb+246272)
    _Float16* h2 = (_Float16*)(ws + 37995024);    // [NN,256] fp16
    float* vf1 = ws;                              // [NN,256] fp32 (x16,h0 dead)
    float* hs  = ws + 16777216;                   // [64,32,256] fp32 (h1 dead)
    float* h3  = vf1;                             // vf1 dead after spec_proj

    dim3 blk(256);

    // ---- prep ----
    cvt16_k<<<16384, blk, 0, stream>>>(x, x16);
    pack_k<256, 256, false><<<32, blk, 0, stream>>>(enc_w, nullptr, enc16);
    pack_k<256, 512, true ><<<64, blk, 0, stream>>>(self_w,         nb_w,         l1w);
    pack_k<256, 512, true ><<<64, blk, 0, stream>>>(self_w + 65536, nb_w + 65536, l2w);
    pack_k<384, 256, false><<<48, blk, 0, stream>>>(dec_w, nullptr, dec16);
    pack_k<256, 256, false><<<32, blk, 0, stream>>>(lin_w, nullptr, lin16);
    bcomb_k<<<2, blk, 0, stream>>>(self_b, nb_b, lbias);
    zero_k<<<64, blk, 0, stream>>>((float*)deg, (size_t)NN);
    hist_k<<<NEDGE / 256, blk, 0, stream>>>(ei, deg);
    scan_k<<<1, 1024, 0, stream>>>(deg, off, cursor);
    fill_k<<<NEDGE / 256, blk, 0, stream>>>(ei, cursor, csr);

    // ---- h0 = gelu(x @ enc_w + enc_b) ----
    mgemm_k<256, 256, false, true, false, false, true><<<dim3(1024), blk, 0, stream>>>(
        x16, nullptr, enc16, enc_b, nullptr, h0);

    // ---- GNN layer 1: h1 = gelu([h0,agg]@W + b) + h0 ----
    gather16_k<<<NN / 4, blk, 0, stream>>>(h0, off, csr, agg);
    mgemm_k<256, 512, true, true, true, false, true><<<dim3(1024), blk, 0, stream>>>(
        h0, agg, l1w, lbias, nullptr, h1);

    // ---- GNN layer 2: h0 = gelu([h1,agg]@W + b) + h1 ----
    gather16_k<<<NN / 4, blk, 0, stream>>>(h1, off, csr, agg);
    mgemm_k<256, 512, true, true, true, false, true><<<dim3(1024), blk, 0, stream>>>(
        h1, agg, l2w, lbias + 256, nullptr, h0);

    // ---- node_rep = h0 @ dec_w + dec_b  (fp16 out; agg+CSR dead) ----
    mgemm_k<384, 256, false, false, false, false, true><<<dim3(1024), dim3(384), 0, stream>>>(
        h0, nullptr, dec16, dec_b, nullptr, nr16);

    // ---- vf1 = Q . x  (x16,h0 dead) ----
    bundle_k<false><<<NN / 4, blk, 0, stream>>>(x, nr16, vf1);

    // ---- spectral filter (scale fused into reproj) ----
    zero_k<<<512, blk, 0, stream>>>(hs, (size_t)GG * KEIG * CH);
    spec_proj_k<<<dim3(GG, 8), blk, 0, stream>>>(vf1, eigvec, hs);
    spec_reproj16_k<<<GG * 16, blk, 0, stream>>>(eigvec, hs, eigval, taus, h2);

    // ---- h3 = h2 @ lin_w + lin_b  (fp32 out; vf1 dead) ----
    mgemm_k<256, 256, false, false, false, true, false><<<dim3(1024), blk, 0, stream>>>(
        h2, nullptr, lin16, lin_b, h3, nullptr);

    // ---- out = Q^T . h3 ----
    bundle_k<true><<<NN / 4, blk, 0, stream>>>(h3, nr16, (float*)d_out);
}

// Round 8
// 688.526 us; speedup vs baseline: 1.0203x; 1.0203x over previous
//
#include <hip/hip_runtime.h>
#include <math.h>

// Problem constants
#define NN      65536
#define GG      64
#define NPG     1024
#define KEIG    32
#define NBUN    64
#define BDIM    4
#define CH      256        // IN_CH == GNN_DIM == NB*BD
#define NBP     384
#define NEDGE   524288

using f16x8 = __attribute__((ext_vector_type(8))) _Float16;
using f16x4 = __attribute__((ext_vector_type(4))) _Float16;
using f32x4 = __attribute__((ext_vector_type(4))) float;

__device__ __forceinline__ float gelu_f(float x) {
    return 0.5f * x * (1.0f + erff(x * 0.70710678118654752440f));
}

// ---------------------------------------------------------------------------
// fp16 MFMA GEMM. Proven: all-coalesced loads (R5, 106->72us), coalesced C16
// epilogue (R6, WRITE 80->33MB, 72->62us), split-K 33KB LDS -> 37% occupancy
// + 3.5TB/s (R7). R7 flaw (counters): launch_bounds(...,4) clamped VGPR to 64
// -> acc(64)+B-prefetch(64) spilled to scratch -> WRITE 111MB / FETCH 99MB of
// spill traffic ate the entire occupancy win (216MB @3.5TB/s = 61us measured).
// R8: launch_bounds(NOUT,3) (cap ~170 VGPR, 3 blocks/CU) + staging register
// footprint cut 8->4 f16x8 (two load-4/write-4 groups; every load instruction
// still a fully-coalesced 1KB). Budget: acc 64 + B 64 + stage 16 + addr ~ 160.
// DUAL: A = concat_k(A1, A2), KTOT=512.  RESA: + A1[m,n] residual (NOUT==256).
// WF: fp32 out (direct; 16 lanes x 4B = full 64B lines).
// W16: fp16 out via LDS-staged coalesced rows.
// Outputs disjoint from ALL inputs (graph-replay safety).
// ---------------------------------------------------------------------------
template<int NOUT, int KTOT, bool DUAL, bool ACT, bool RESA, bool WF, bool W16>
__global__ __launch_bounds__(NOUT, 3) void mgemm_k(
    const _Float16* __restrict__ A1, const _Float16* __restrict__ A2,
    const _Float16* __restrict__ Bp, const float* __restrict__ bias,
    float* __restrict__ Cf, _Float16* __restrict__ C16)
{
    constexpr int NT   = KTOT / 32;     // total K-steps (8 or 16)
    constexpr int HALVES = KTOT / 256;  // 1 or 2 half-panels of K=256
    constexpr int ROWB = 512;           // LDS bytes per A row (K=256 half)
    constexpr int CPR  = 32;            // 16B chunks per A row (half)
    constexpr int TOTC = 64 * CPR;      // 2048 chunks per half-panel
    constexpr int NSTG = TOTC / NOUT;   // full stage iters per thread
    constexpr int CTS  = NOUT + 8;      // padded C-tile row stride (halfs)
    constexpr int AH   = 64 * 256;      // A half-panel halfs (32 KB)
    constexpr int CTH  = 64 * CTS;
    constexpr int LDSH = (W16 && CTH > AH) ? CTH : AH;
    __shared__ _Float16 Alds[LDSH];

    const int tid  = threadIdx.x;
    const int lane = tid & 63;
    const int wave = tid >> 6;          // wave owns cols wave*64..wave*64+63
    const int m0   = blockIdx.x * 64;   // block's 64 A rows

    const int r16 = lane & 15;          // fragment row / col within 16
    const int kc  = lane >> 4;          // k-chunk 0..3

    // B packed: chunk((wn*NT + t)*4 + q), lane-contiguous 16B each
    const _Float16* bpp = Bp + ((size_t)wave * NT * 2048) + lane * 8;

    f16x8 pa0, pa1, pa2, pa3, pb0, pb1, pb2, pb3;
    f16x8 pc0, pc1, pc2, pc3, pd0, pd1, pd2, pd3;

#define LDB(P0, P1, P2, P3, T)                                                 \
    {                                                                          \
        const _Float16* bq_ = bpp + (size_t)(T) * 2048;                        \
        P0 = *(const f16x8*)(bq_);                                             \
        P1 = *(const f16x8*)(bq_ + 512);                                       \
        P2 = *(const f16x8*)(bq_ + 1024);                                      \
        P3 = *(const f16x8*)(bq_ + 1536);                                      \
    }

    // stage one 64x256 half-panel: groups of 4 coalesced 1KB loads -> regs ->
    // swizzled LDS (16 VGPRs of staging state instead of 32)
    auto stage = [&](const _Float16* __restrict__ BASE) {
#pragma unroll
        for (int j0 = 0; j0 < NSTG; j0 += 4) {
            f16x8 s0, s1, s2, s3;
            const int nv = (NSTG - j0 >= 4) ? 4 : (NSTG - j0);
            int i0 = tid + (j0 + 0) * NOUT;
            int i1 = tid + (j0 + 1) * NOUT;
            int i2 = tid + (j0 + 2) * NOUT;
            int i3 = tid + (j0 + 3) * NOUT;
            if (nv > 0) s0 = *(const f16x8*)(BASE + (size_t)(m0 + (i0 >> 5)) * 256 + (i0 & 31) * 8);
            if (nv > 1) s1 = *(const f16x8*)(BASE + (size_t)(m0 + (i1 >> 5)) * 256 + (i1 & 31) * 8);
            if (nv > 2) s2 = *(const f16x8*)(BASE + (size_t)(m0 + (i2 >> 5)) * 256 + (i2 & 31) * 8);
            if (nv > 3) s3 = *(const f16x8*)(BASE + (size_t)(m0 + (i3 >> 5)) * 256 + (i3 & 31) * 8);
            if (nv > 0) *(f16x8*)((char*)Alds + ((((i0 >> 5) * ROWB + (i0 & 31) * 16)) ^ (((i0 >> 5) & 7) << 4))) = s0;
            if (nv > 1) *(f16x8*)((char*)Alds + ((((i1 >> 5) * ROWB + (i1 & 31) * 16)) ^ (((i1 >> 5) & 7) << 4))) = s1;
            if (nv > 2) *(f16x8*)((char*)Alds + ((((i2 >> 5) * ROWB + (i2 & 31) * 16)) ^ (((i2 >> 5) & 7) << 4))) = s2;
            if (nv > 3) *(f16x8*)((char*)Alds + ((((i3 >> 5) * ROWB + (i3 & 31) * 16)) ^ (((i3 >> 5) & 7) << 4))) = s3;
        }
        if (TOTC % NOUT) {              // remainder (NOUT=384 case)
            const int idx = tid + NSTG * NOUT;
            if (idx < TOTC) {
                const int r = idx >> 5, c = idx & 31;
                f16x8 v = *(const f16x8*)(BASE + (size_t)(m0 + r) * 256 + c * 8);
                *(f16x8*)((char*)Alds + ((r * ROWB + c * 16) ^ ((r & 7) << 4))) = v;
            }
        }
    };

    // issue B prefetch for steps 0..3 BEFORE staging (overlaps A latency)
    LDB(pa0, pa1, pa2, pa3, 0)
    LDB(pb0, pb1, pb2, pb3, 1)
    LDB(pc0, pc1, pc2, pc3, 2)
    LDB(pd0, pd1, pd2, pd3, 3)

    stage(A1);
    __syncthreads();

    f32x4 acc[4][4];
#pragma unroll
    for (int i = 0; i < 4; i++)
#pragma unroll
        for (int j = 0; j < 4; j++) acc[i][j] = 0.f;

#define MSTEP(OFF, P0, P1, P2, P3)                                             \
    {                                                                          \
        const char* ap_ = (const char*)Alds + (OFF);                           \
        f16x8 a0_ = *(const f16x8*)(ap_);                                      \
        f16x8 a1_ = *(const f16x8*)(ap_ + 16 * ROWB);                          \
        f16x8 a2_ = *(const f16x8*)(ap_ + 32 * ROWB);                          \
        f16x8 a3_ = *(const f16x8*)(ap_ + 48 * ROWB);                          \
        acc[0][0] = __builtin_amdgcn_mfma_f32_16x16x32_f16(a0_, P0, acc[0][0], 0, 0, 0); \
        acc[0][1] = __builtin_amdgcn_mfma_f32_16x16x32_f16(a0_, P1, acc[0][1], 0, 0, 0); \
        acc[0][2] = __builtin_amdgcn_mfma_f32_16x16x32_f16(a0_, P2, acc[0][2], 0, 0, 0); \
        acc[0][3] = __builtin_amdgcn_mfma_f32_16x16x32_f16(a0_, P3, acc[0][3], 0, 0, 0); \
        acc[1][0] = __builtin_amdgcn_mfma_f32_16x16x32_f16(a1_, P0, acc[1][0], 0, 0, 0); \
        acc[1][1] = __builtin_amdgcn_mfma_f32_16x16x32_f16(a1_, P1, acc[1][1], 0, 0, 0); \
        acc[1][2] = __builtin_amdgcn_mfma_f32_16x16x32_f16(a1_, P2, acc[1][2], 0, 0, 0); \
        acc[1][3] = __builtin_amdgcn_mfma_f32_16x16x32_f16(a1_, P3, acc[1][3], 0, 0, 0); \
        acc[2][0] = __builtin_amdgcn_mfma_f32_16x16x32_f16(a2_, P0, acc[2][0], 0, 0, 0); \
        acc[2][1] = __builtin_amdgcn_mfma_f32_16x16x32_f16(a2_, P1, acc[2][1], 0, 0, 0); \
        acc[2][2] = __builtin_amdgcn_mfma_f32_16x16x32_f16(a2_, P2, acc[2][2], 0, 0, 0); \
        acc[2][3] = __builtin_amdgcn_mfma_f32_16x16x32_f16(a2_, P3, acc[2][3], 0, 0, 0); \
        acc[3][0] = __builtin_amdgcn_mfma_f32_16x16x32_f16(a3_, P0, acc[3][0], 0, 0, 0); \
        acc[3][1] = __builtin_amdgcn_mfma_f32_16x16x32_f16(a3_, P1, acc[3][1], 0, 0, 0); \
        acc[3][2] = __builtin_amdgcn_mfma_f32_16x16x32_f16(a3_, P2, acc[3][2], 0, 0, 0); \
        acc[3][3] = __builtin_amdgcn_mfma_f32_16x16x32_f16(a3_, P3, acc[3][3], 0, 0, 0); \
    }

    const int swz = (r16 & 7) << 4;
#pragma unroll
    for (int h = 0; h < HALVES; ++h) {
        if (h > 0) {
            __syncthreads();            // all waves done reading half 0
            stage(A2);
            __syncthreads();
        }
        int au = r16 * ROWB + kc * 16;
#pragma unroll
        for (int tt = 0; tt < 8; tt += 4) {
            const int t = h * 8 + tt;   // global K-step for B indexing
            MSTEP((au      ) ^ swz, pa0, pa1, pa2, pa3)
            if (t + 4 < NT) LDB(pa0, pa1, pa2, pa3, t + 4)
            MSTEP((au +  64) ^ swz, pb0, pb1, pb2, pb3)
            if (t + 5 < NT) LDB(pb0, pb1, pb2, pb3, t + 5)
            MSTEP((au + 128) ^ swz, pc0, pc1, pc2, pc3)
            if (t + 6 < NT) LDB(pc0, pc1, pc2, pc3, t + 6)
            MSTEP((au + 192) ^ swz, pd0, pd1, pd2, pd3)
            if (t + 7 < NT) LDB(pd0, pd1, pd2, pd3, t + 7)
            au += 256;
        }
    }
#undef LDB
#undef MSTEP

    // epilogue: C[m = quad*4+reg][n = lane&15] per 16x16 tile (m89 layout)
    const int rbase = (lane >> 4) * 4;
    const int ncol  = lane & 15;
    if constexpr (W16) {
        __syncthreads();                // all waves done reading Alds
        constexpr int CPRN = NOUT / 8;  // 16B chunks per C row
        constexpr int CPT  = 64 * CPRN / NOUT;   // chunks per thread (= 8)
        // issue coalesced residual loads early (hide under gelu VALU work)
        f16x8 res[CPT];
        if constexpr (RESA) {
#pragma unroll
            for (int k2 = 0; k2 < CPT; k2++) {
                const int c = tid + k2 * NOUT;
                const int row = c / CPRN, col = c - row * CPRN;
                res[k2] = *(const f16x8*)(A1 + (size_t)(m0 + row) * 256 + col * 8);
            }
        }
        // scatter bias+act into padded LDS C-tile
#pragma unroll
        for (int nt = 0; nt < 4; nt++) {
            const int n = wave * 64 + nt * 16 + ncol;
            const float bs = bias[n];
#pragma unroll
            for (int mt = 0; mt < 4; mt++) {
#pragma unroll
                for (int i = 0; i < 4; i++) {
                    const int mr = mt * 16 + rbase + i;
                    float v = acc[mt][nt][i] + bs;
                    if (ACT) v = gelu_f(v);
                    Alds[mr * CTS + n] = (_Float16)v;
                }
            }
        }
        __syncthreads();
        // coalesced row-write (+ packed fp16 residual add)
#pragma unroll
        for (int k2 = 0; k2 < CPT; k2++) {
            const int c = tid + k2 * NOUT;
            const int row = c / CPRN, col = c - row * CPRN;
            f16x8 v = *(const f16x8*)&Alds[row * CTS + col * 8];
            if constexpr (RESA) v = v + res[k2];
            *(f16x8*)(C16 + (size_t)(m0 + row) * NOUT + col * 8) = v;
        }
    } else {
#pragma unroll
        for (int nt = 0; nt < 4; nt++) {
            const int n = wave * 64 + nt * 16 + ncol;
            const float bs = bias[n];
#pragma unroll
            for (int mt = 0; mt < 4; mt++) {
#pragma unroll
                for (int i = 0; i < 4; i++) {
                    const int m = m0 + mt * 16 + rbase + i;
                    float v = acc[mt][nt][i] + bs;
                    if (ACT) v = gelu_f(v);
                    if (RESA) v += (float)A1[(size_t)m * 256 + n];
                    if (WF) Cf[(size_t)m * NOUT + n] = v;
                }
            }
        }
    }
}

// ---------------------------------------------------------------------------
// Weight pack: fp32 W[k][n] (k-major, row stride NOUT) -> fragment-ordered
// fp16 chunks. Chunk cid = ((wn*NT + t)*4 + q)*64 + l holds 8 halfs:
// value[j] = W[t*32 + (l>>4)*8 + j][wn*64 + q*16 + (l&15)].
// DUAL: k >= 256 reads W2[k-256][n].
// ---------------------------------------------------------------------------
template<int NOUT, int KTOT, bool DUAL>
__global__ __launch_bounds__(256) void pack_k(
    const float* __restrict__ W1, const float* __restrict__ W2,
    _Float16* __restrict__ Bp)
{
    constexpr int NT = KTOT / 32;
    const int cid = blockIdx.x * 256 + threadIdx.x;
    if (cid >= NOUT * KTOT / 8) return;
    const int l  = cid & 63;
    const int q  = (cid >> 6) & 3;
    const int c2 = cid >> 8;            // wn*NT + t
    const int t  = c2 & (NT - 1);
    const int wn = c2 / NT;
    const int n  = wn * 64 + q * 16 + (l & 15);
    const int k0 = t * 32 + (l >> 4) * 8;
    f16x8 v;
#pragma unroll
    for (int j = 0; j < 8; j++) {
        const int k = k0 + j;
        float w = (DUAL && k >= 256) ? W2[(size_t)(k - 256) * NOUT + n]
                                     : W1[(size_t)k * NOUT + n];
        v[j] = (_Float16)w;
    }
    *(f16x8*)(Bp + (size_t)cid * 8) = v;
}

// ---------------------------------------------------------------------------
__global__ void zero_k(float* __restrict__ p, size_t n)
{
    size_t i = (size_t)blockIdx.x * blockDim.x + threadIdx.x;
    float4* p4 = (float4*)p;
    size_t n4 = n >> 2;
    for (size_t j = i; j < n4; j += (size_t)gridDim.x * blockDim.x)
        p4[j] = make_float4(0.f, 0.f, 0.f, 0.f);
}

// fp32 -> fp16 convert (4 elems/thread)
__global__ __launch_bounds__(256) void cvt16_k(
    const float* __restrict__ in, _Float16* __restrict__ out)
{
    size_t i = (size_t)blockIdx.x * 256 + threadIdx.x;
    float4 v = ((const float4*)in)[i];
    f16x4 o = { (_Float16)v.x, (_Float16)v.y, (_Float16)v.z, (_Float16)v.w };
    ((f16x4*)out)[i] = o;
}

__global__ void bcomb_k(const float* __restrict__ a, const float* __restrict__ b,
                        float* __restrict__ o)
{
    int i = blockIdx.x * 256 + threadIdx.x;
    if (i < 512) o[i] = a[i] + b[i];
}

// ---------------------------------------------------------------------------
// CSR build: histogram of dst, exclusive scan, cursor fill
// ---------------------------------------------------------------------------
__global__ __launch_bounds__(256) void hist_k(const int* __restrict__ ei, int* __restrict__ deg)
{
    int e = blockIdx.x * 256 + threadIdx.x;
    if (e < NEDGE) atomicAdd(&deg[ei[NEDGE + e]], 1);
}

__global__ __launch_bounds__(1024) void scan_k(
    const int* __restrict__ deg, int* __restrict__ off, int* __restrict__ cursor)
{
    __shared__ int sh[1024];
    const int tid = threadIdx.x;
    const int base = tid * 64;
    int s = 0;
#pragma unroll 8
    for (int i = 0; i < 64; i++) s += deg[base + i];
    const int mysum = s;
    sh[tid] = s;
    __syncthreads();
    for (int ofs = 1; ofs < 1024; ofs <<= 1) {
        int v = (tid >= ofs) ? sh[tid - ofs] : 0;
        __syncthreads();
        sh[tid] += v;
        __syncthreads();
    }
    int running = sh[tid] - mysum;
    for (int i = 0; i < 64; i++) {
        off[base + i] = running;
        cursor[base + i] = running;
        running += deg[base + i];
    }
    if (tid == 1023) off[NN] = running;
}

__global__ __launch_bounds__(256) void fill_k(
    const int* __restrict__ ei, int* __restrict__ cursor, int* __restrict__ csr)
{
    int e = blockIdx.x * 256 + threadIdx.x;
    if (e < NEDGE) {
        int d = ei[NEDGE + e];
        int pos = atomicAdd(&cursor[d], 1);
        csr[pos] = ei[e];   // src
    }
}

// ---------------------------------------------------------------------------
// Gather segment-sum over fp16 h: fp32 accum, fp16 out. 4 rows in flight.
// ---------------------------------------------------------------------------
__global__ __launch_bounds__(256) void gather16_k(
    const _Float16* __restrict__ h, const int* __restrict__ off,
    const int* __restrict__ csr, _Float16* __restrict__ agg)
{
    const int lane = threadIdx.x & 63;
    const int n = blockIdx.x * 4 + (threadIdx.x >> 6);
    const int s0 = off[n], s1 = off[n + 1];
    float a0 = 0.f, a1 = 0.f, a2 = 0.f, a3 = 0.f;
    int j = s0;
    for (; j + 3 < s1; j += 4) {
        const int i0 = csr[j], i1 = csr[j + 1], i2 = csr[j + 2], i3 = csr[j + 3];
        f16x4 v0 = ((const f16x4*)(h + (size_t)i0 * CH))[lane];
        f16x4 v1 = ((const f16x4*)(h + (size_t)i1 * CH))[lane];
        f16x4 v2 = ((const f16x4*)(h + (size_t)i2 * CH))[lane];
        f16x4 v3 = ((const f16x4*)(h + (size_t)i3 * CH))[lane];
        a0 += (float)v0[0] + (float)v1[0] + (float)v2[0] + (float)v3[0];
        a1 += (float)v0[1] + (float)v1[1] + (float)v2[1] + (float)v3[1];
        a2 += (float)v0[2] + (float)v1[2] + (float)v2[2] + (float)v3[2];
        a3 += (float)v0[3] + (float)v1[3] + (float)v2[3] + (float)v3[3];
    }
    for (; j < s1; j++) {
        f16x4 va = ((const f16x4*)(h + (size_t)csr[j] * CH))[lane];
        a0 += (float)va[0]; a1 += (float)va[1]; a2 += (float)va[2]; a3 += (float)va[3];
    }
    f16x4 o = { (_Float16)a0, (_Float16)a1, (_Float16)a2, (_Float16)a3 };
    ((f16x4*)(agg + (size_t)n * CH))[lane] = o;
}

// ---------------------------------------------------------------------------
// Householder Q from 6 fp16 params (BD=4: 3 reflectors)
// ---------------------------------------------------------------------------
__device__ __forceinline__ void make_Q(const _Float16* __restrict__ p, float Q[4][4])
{
#pragma unroll
    for (int i = 0; i < 4; i++)
#pragma unroll
        for (int j = 0; j < 4; j++) Q[i][j] = (i == j) ? 1.f : 0.f;
    int idx = 0;
#pragma unroll
    for (int j = 0; j < 3; j++) {
        float v[4] = {0.f, 0.f, 0.f, 0.f};
        v[j] = 1.f;
#pragma unroll
        for (int t = 0; t < 4; t++)
            if (t > j) v[t] = (float)p[idx + t - (j + 1)];
        idx += 3 - j;
        float nrm = v[0]*v[0] + v[1]*v[1] + v[2]*v[2] + v[3]*v[3];
        float s = 2.f / nrm;
#pragma unroll
        for (int i = 0; i < 4; i++) {
            float qv = Q[i][0]*v[0] + Q[i][1]*v[1] + Q[i][2]*v[2] + Q[i][3]*v[3];
            float t0 = s * qv;
#pragma unroll
            for (int c = 0; c < 4; c++) Q[i][c] -= t0 * v[c];
        }
    }
}

// Bundle transform: block = 4 nodes x 64 bundles; node_rep is fp16
template<bool TRANS>
__global__ __launch_bounds__(256) void bundle_k(
    const float* __restrict__ vin, const _Float16* __restrict__ nr,
    float* __restrict__ out)
{
    __shared__ _Float16 pb[4 * NBP];
    const int n0 = blockIdx.x * 4;
    for (int i = threadIdx.x; i < 4 * NBP; i += 256)
        pb[i] = nr[(size_t)n0 * NBP + i];
    __syncthreads();
    const int ln = threadIdx.x >> 6;
    const int b  = threadIdx.x & 63;
    const int n  = n0 + ln;
    float Q[4][4];
    make_Q(&pb[ln * NBP + b * 6], Q);
    float4 xv = ((const float4*)(vin + (size_t)n * CH))[b];
    float in0 = xv.x, in1 = xv.y, in2 = xv.z, in3 = xv.w;
    float4 o;
    if constexpr (!TRANS) {
        o.x = Q[0][0]*in0 + Q[0][1]*in1 + Q[0][2]*in2 + Q[0][3]*in3;
        o.y = Q[1][0]*in0 + Q[1][1]*in1 + Q[1][2]*in2 + Q[1][3]*in3;
        o.z = Q[2][0]*in0 + Q[2][1]*in1 + Q[2][2]*in2 + Q[2][3]*in3;
        o.w = Q[3][0]*in0 + Q[3][1]*in1 + Q[3][2]*in2 + Q[3][3]*in3;
    } else {
        o.x = Q[0][0]*in0 + Q[1][0]*in1 + Q[2][0]*in2 + Q[3][0]*in3;
        o.y = Q[0][1]*in0 + Q[1][1]*in1 + Q[2][1]*in2 + Q[3][1]*in3;
        o.z = Q[0][2]*in0 + Q[1][2]*in1 + Q[2][2]*in2 + Q[3][2]*in3;
        o.w = Q[0][3]*in0 + Q[1][3]*in1 + Q[2][3]*in2 + Q[3][3]*in3;
    }
    ((float4*)(out + (size_t)n * CH))[b] = o;
}

// ---------------------------------------------------------------------------
// Spectral kernels
// ---------------------------------------------------------------------------
__global__ __launch_bounds__(256) void spec_proj_k(
    const float* __restrict__ v, const float* __restrict__ eigvec, float* __restrict__ hs)
{
    const int g = blockIdx.x;
    const int nbase = g * NPG + blockIdx.y * 128;
    __shared__ float evs[16][32];
    float acc[32];
#pragma unroll
    for (int k = 0; k < 32; k++) acc[k] = 0.f;
    for (int nt = 0; nt < 128; nt += 16) {
        __syncthreads();
        for (int i = threadIdx.x; i < 512; i += 256) {
            int nn = i >> 5, kk = i & 31;
            evs[nn][kk] = eigvec[(size_t)(nbase + nt + nn) * KEIG + kk];
        }
        __syncthreads();
#pragma unroll 4
        for (int nn = 0; nn < 16; nn++) {
            float hv = v[(size_t)(nbase + nt + nn) * CH + threadIdx.x];
#pragma unroll
            for (int k = 0; k < 32; k++) acc[k] += evs[nn][k] * hv;
        }
    }
    float* o = hs + (size_t)g * KEIG * CH + threadIdx.x;
#pragma unroll
    for (int k = 0; k < 32; k++) atomicAdd(o + k * CH, acc[k]);
}

// out16[g,n,d] = sum_v ev[g,n,v] * hs[g,v,d] * exp(-eigval[g,v]*taus[d>>2])
// (spec_scale fused into the hs load)
__global__ __launch_bounds__(256) void spec_reproj16_k(
    const float* __restrict__ eigvec, const float* __restrict__ hs,
    const float* __restrict__ eigval, const float* __restrict__ taus,
    _Float16* __restrict__ out16)
{
    const int g = blockIdx.x >> 4;
    const int nbase = g * NPG + (blockIdx.x & 15) * 64;
    const float tau = taus[threadIdx.x >> 2];
    float hsr[32];
    const float* hg = hs + (size_t)g * KEIG * CH + threadIdx.x;
#pragma unroll
    for (int k = 0; k < 32; k++)
        hsr[k] = hg[k * CH] * expf(-eigval[g * KEIG + k] * tau);
    __shared__ float evs[64][32];
    for (int i = threadIdx.x; i < 2048; i += 256) {
        int nn = i >> 5, kk = i & 31;
        evs[nn][kk] = eigvec[(size_t)(nbase + nn) * KEIG + kk];
    }
    __syncthreads();
    for (int nn = 0; nn < 64; nn++) {
        float a = 0.f;
#pragma unroll
        for (int k = 0; k < 32; k++) a += evs[nn][k] * hsr[k];
        out16[(size_t)(nbase + nn) * CH + threadIdx.x] = (_Float16)a;
    }
}

// ---------------------------------------------------------------------------
extern "C" void kernel_launch(void* const* d_in, const int* in_sizes, int n_in,
                              void* d_out, int out_size, void* d_ws, size_t ws_size,
                              hipStream_t stream)
{
    const float* x      = (const float*)d_in[0];
    const float* eigvec = (const float*)d_in[1];
    const float* eigval = (const float*)d_in[2];
    const float* taus   = (const float*)d_in[3];
    const float* enc_w  = (const float*)d_in[4];
    const float* enc_b  = (const float*)d_in[5];
    const float* self_w = (const float*)d_in[6];
    const float* self_b = (const float*)d_in[7];
    const float* nb_w   = (const float*)d_in[8];
    const float* nb_b   = (const float*)d_in[9];
    const float* dec_w  = (const float*)d_in[10];
    const float* dec_b  = (const float*)d_in[11];
    const float* lin_w  = (const float*)d_in[12];
    const float* lin_b  = (const float*)d_in[13];
    const int*   ei     = (const int*)d_in[14];
    (void)in_sizes; (void)n_in; (void)out_size; (void)ws_size;

    float* ws = (float*)d_ws;
    // Stream-ordered lifetimes (float-slot offsets):
    //  [0,        8388608)  x16          -> vf1[0:half] / h3
    //  [8388608, 16777216)  h0           -> vf1[half:]  / h3
    //  [16777216,25165824)  h1           -> hs (@16.7M) ; free tail
    //  [25165824,33554432)  agg          -> nr16 part
    //  [33554432,34275329)  CSR ints     -> nr16 part
    //  [25165824,37748736)  nr16 [NN,384] fp16 (dec out; agg+CSR dead)
    //  [37748752,37995024)  packed weights + lbias
    //  [37995024,46383632)  h2 [NN,256] fp16
    // high-water: 46,383,632 fl = 185.5 MB
    _Float16* x16 = (_Float16*)(ws);
    _Float16* h0  = (_Float16*)(ws + 8388608);
    _Float16* h1  = (_Float16*)(ws + 16777216);
    _Float16* agg = (_Float16*)(ws + 25165824);
    int* ibase  = (int*)(ws + 33554432);
    int* deg    = ibase;                 // NN
    int* off    = ibase + 65536;         // NN+1
    int* cursor = ibase + 131073;        // NN
    int* csr    = ibase + 196609;        // NEDGE (ends slot 34275329)
    _Float16* nr16 = (_Float16*)(ws + 25165824);  // [NN,384] fp16
    float* wb = ws + 37748752;
    _Float16* enc16 = (_Float16*)(wb);            // packed [256x256]
    _Float16* l1w   = (_Float16*)(wb + 32768);    // packed [256x512]
    _Float16* l2w   = (_Float16*)(wb + 98304);    // packed [256x512]
    _Float16* dec16 = (_Float16*)(wb + 163840);   // packed [384x256]
    _Float16* lin16 = (_Float16*)(wb + 212992);   // packed [256x256]
    float* lbias = wb + 245760;                   // [2,256] (ends wb+246272)
    _Float16* h2 = (_Float16*)(ws + 37995024);    // [NN,256] fp16
    float* vf1 = ws;                              // [NN,256] fp32 (x16,h0 dead)
    float* hs  = ws + 16777216;                   // [64,32,256] fp32 (h1 dead)
    float* h3  = vf1;                             // vf1 dead after spec_proj

    dim3 blk(256);

    // ---- prep ----
    cvt16_k<<<16384, blk, 0, stream>>>(x, x16);
    pack_k<256, 256, false><<<32, blk, 0, stream>>>(enc_w, nullptr, enc16);
    pack_k<256, 512, true ><<<64, blk, 0, stream>>>(self_w,         nb_w,         l1w);
    pack_k<256, 512, true ><<<64, blk, 0, stream>>>(self_w + 65536, nb_w + 65536, l2w);
    pack_k<384, 256, false><<<48, blk, 0, stream>>>(dec_w, nullptr, dec16);
    pack_k<256, 256, false><<<32, blk, 0, stream>>>(lin_w, nullptr, lin16);
    bcomb_k<<<2, blk, 0, stream>>>(self_b, nb_b, lbias);
    zero_k<<<64, blk, 0, stream>>>((float*)deg, (size_t)NN);
    hist_k<<<NEDGE / 256, blk, 0, stream>>>(ei, deg);
    scan_k<<<1, 1024, 0, stream>>>(deg, off, cursor);
    fill_k<<<NEDGE / 256, blk, 0, stream>>>(ei, cursor, csr);

    // ---- h0 = gelu(x @ enc_w + enc_b) ----
    mgemm_k<256, 256, false, true, false, false, true><<<dim3(1024), blk, 0, stream>>>(
        x16, nullptr, enc16, enc_b, nullptr, h0);

    // ---- GNN layer 1: h1 = gelu([h0,agg]@W + b) + h0 ----
    gather16_k<<<NN / 4, blk, 0, stream>>>(h0, off, csr, agg);
    mgemm_k<256, 512, true, true, true, false, true><<<dim3(1024), blk, 0, stream>>>(
        h0, agg, l1w, lbias, nullptr, h1);

    // ---- GNN layer 2: h0 = gelu([h1,agg]@W + b) + h1 ----
    gather16_k<<<NN / 4, blk, 0, stream>>>(h1, off, csr, agg);
    mgemm_k<256, 512, true, true, true, false, true><<<dim3(1024), blk, 0, stream>>>(
        h1, agg, l2w, lbias + 256, nullptr, h0);

    // ---- node_rep = h0 @ dec_w + dec_b  (fp16 out; agg+CSR dead) ----
    mgemm_k<384, 256, false, false, false, false, true><<<dim3(1024), dim3(384), 0, stream>>>(
        h0, nullptr, dec16, dec_b, nullptr, nr16);

    // ---- vf1 = Q . x  (x16,h0 dead) ----
    bundle_k<false><<<NN / 4, blk, 0, stream>>>(x, nr16, vf1);

    // ---- spectral filter (scale fused into reproj) ----
    zero_k<<<512, blk, 0, stream>>>(hs, (size_t)GG * KEIG * CH);
    spec_proj_k<<<dim3(GG, 8), blk, 0, stream>>>(vf1, eigvec, hs);
    spec_reproj16_k<<<GG * 16, blk, 0, stream>>>(eigvec, hs, eigval, taus, h2);

    // ---- h3 = h2 @ lin_w + lin_b  (fp32 out; vf1 dead) ----
    mgemm_k<256, 256, false, false, false, true, false><<<dim3(1024), blk, 0, stream>>>(
        h2, nullptr, lin16, lin_b, h3, nullptr);

    // ---- out = Q^T . h3 ----
    bundle_k<true><<<NN / 4, blk, 0, stream>>>(h3, nr16, (float*)d_out);
}

// Round 9
// 637.452 us; speedup vs baseline: 1.1021x; 1.0801x over previous
//
#include <hip/hip_runtime.h>
#include <math.h>

// Problem constants
#define NN      65536
#define GG      64
#define NPG     1024
#define KEIG    32
#define NBUN    64
#define BDIM    4
#define CH      256        // IN_CH == GNN_DIM == NB*BD
#define NBP     384
#define NEDGE   524288

using f16x8 = __attribute__((ext_vector_type(8))) _Float16;
using f16x4 = __attribute__((ext_vector_type(4))) _Float16;
using f32x4 = __attribute__((ext_vector_type(4))) float;

__device__ __forceinline__ float gelu_f(float x) {
    return 0.5f * x * (1.0f + erff(x * 0.70710678118654752440f));
}

// ---------------------------------------------------------------------------
// Householder Q from 6 fp16 params (BD=4: 3 reflectors)
// ---------------------------------------------------------------------------
__device__ __forceinline__ void make_Q(const _Float16* __restrict__ p, float Q[4][4])
{
#pragma unroll
    for (int i = 0; i < 4; i++)
#pragma unroll
        for (int j = 0; j < 4; j++) Q[i][j] = (i == j) ? 1.f : 0.f;
    int idx = 0;
#pragma unroll
    for (int j = 0; j < 3; j++) {
        float v[4] = {0.f, 0.f, 0.f, 0.f};
        v[j] = 1.f;
#pragma unroll
        for (int t = 0; t < 4; t++)
            if (t > j) v[t] = (float)p[idx + t - (j + 1)];
        idx += 3 - j;
        float nrm = v[0]*v[0] + v[1]*v[1] + v[2]*v[2] + v[3]*v[3];
        float s = 2.f / nrm;
#pragma unroll
        for (int i = 0; i < 4; i++) {
            float qv = Q[i][0]*v[0] + Q[i][1]*v[1] + Q[i][2]*v[2] + Q[i][3]*v[3];
            float t0 = s * qv;
#pragma unroll
            for (int c = 0; c < 4; c++) Q[i][c] -= t0 * v[c];
        }
    }
}

// ---------------------------------------------------------------------------
// fp16 MFMA GEMM (R8 core, proven: all-coalesced loads, split-K 33KB staging,
// coalesced W16 epilogue). DUAL GEMM parked at ~62us (R6/R7/R8 all ~62 across
// three schedule variants -> structural plateau; further rounds target the
// ~560us of non-top-5 dispatches via FUSION):
//  A32: stage A directly from fp32 (kills the cvt16 pass).
//  BUN==1 (dec): epilogue ALSO computes vf16 = Q . x using the Q-params
//    sitting in the LDS C-tile (kills the bundle<false> launch).
//  BUN==2 (lin): fp32 LDS C-tile + per-(row,bundle) Q^T transform written
//    straight to d_out (kills h3 write+read and the bundle<true> launch;
//    numerics identical to old fp32 h3 path).
// DUAL: A = concat_k(A1, A2), KTOT=512.  RESA: + A1[m,n] residual (NOUT==256).
// Outputs disjoint from ALL inputs (graph-replay safety).
// ---------------------------------------------------------------------------
template<int NOUT, int KTOT, bool DUAL, bool ACT, bool RESA, bool W16, bool A32, int BUN>
__global__ __launch_bounds__(NOUT, 3) void mgemm_k(
    const _Float16* __restrict__ A1, const _Float16* __restrict__ A2,
    const float* __restrict__ A1f, const _Float16* __restrict__ Bp,
    const float* __restrict__ bias, _Float16* __restrict__ C16,
    const float* __restrict__ xin, _Float16* __restrict__ vf16,
    const _Float16* __restrict__ nrq, float* __restrict__ outf)
{
    constexpr int NT   = KTOT / 32;     // total K-steps (8 or 16)
    constexpr int HALVES = KTOT / 256;  // 1 or 2 half-panels of K=256
    constexpr int ROWB = 512;           // LDS bytes per A row (K=256 half)
    constexpr int CPR  = 32;            // 16B chunks per A row (half)
    constexpr int TOTC = 64 * CPR;      // 2048 chunks per half-panel
    constexpr int NSTG = TOTC / NOUT;   // full stage iters per thread
    constexpr int CTS  = NOUT + 8;      // padded C-tile row stride (halfs)
    constexpr int AH   = 64 * 256;      // A half-panel halfs (32 KB)
    constexpr int W16H = W16 ? 64 * CTS : 0;
    constexpr int B2H  = (BUN == 2) ? 64 * CTS * 2 : 0;   // fp32 tile as halfs
    constexpr int LDSH = (AH > W16H) ? ((AH > B2H) ? AH : B2H)
                                     : ((W16H > B2H) ? W16H : B2H);
    __shared__ _Float16 Alds[LDSH];

    const int tid  = threadIdx.x;
    const int lane = tid & 63;
    const int wave = tid >> 6;          // wave owns cols wave*64..wave*64+63
    const int m0   = blockIdx.x * 64;   // block's 64 A rows

    const int r16 = lane & 15;          // fragment row / col within 16
    const int kc  = lane >> 4;          // k-chunk 0..3

    // B packed: chunk((wn*NT + t)*4 + q), lane-contiguous 16B each
    const _Float16* bpp = Bp + ((size_t)wave * NT * 2048) + lane * 8;

    f16x8 pa0, pa1, pa2, pa3, pb0, pb1, pb2, pb3;
    f16x8 pc0, pc1, pc2, pc3, pd0, pd1, pd2, pd3;

#define LDB(P0, P1, P2, P3, T)                                                 \
    {                                                                          \
        const _Float16* bq_ = bpp + (size_t)(T) * 2048;                        \
        P0 = *(const f16x8*)(bq_);                                             \
        P1 = *(const f16x8*)(bq_ + 512);                                       \
        P2 = *(const f16x8*)(bq_ + 1024);                                      \
        P3 = *(const f16x8*)(bq_ + 1536);                                      \
    }

    // coalesced A-chunk load (fp16 direct, or fp32 + inline cvt when A32)
    auto ldA = [&](const _Float16* B16, const float* B32, int idx) -> f16x8 {
        const size_t off = (size_t)(m0 + (idx >> 5)) * 256 + (idx & 31) * 8;
        if constexpr (A32) {
            float4 lo = *(const float4*)(B32 + off);
            float4 hi = *(const float4*)(B32 + off + 4);
            f16x8 r = { (_Float16)lo.x, (_Float16)lo.y, (_Float16)lo.z, (_Float16)lo.w,
                        (_Float16)hi.x, (_Float16)hi.y, (_Float16)hi.z, (_Float16)hi.w };
            return r;
        } else {
            return *(const f16x8*)(B16 + off);
        }
    };

    // stage one 64x256 half-panel: groups of 4 coalesced loads -> regs ->
    // swizzled LDS (16 VGPRs of staging state)
    auto stage = [&](const _Float16* B16, const float* B32) {
#pragma unroll
        for (int j0 = 0; j0 < NSTG; j0 += 4) {
            f16x8 s0, s1, s2, s3;
            const int nv = (NSTG - j0 >= 4) ? 4 : (NSTG - j0);
            int i0 = tid + (j0 + 0) * NOUT;
            int i1 = tid + (j0 + 1) * NOUT;
            int i2 = tid + (j0 + 2) * NOUT;
            int i3 = tid + (j0 + 3) * NOUT;
            if (nv > 0) s0 = ldA(B16, B32, i0);
            if (nv > 1) s1 = ldA(B16, B32, i1);
            if (nv > 2) s2 = ldA(B16, B32, i2);
            if (nv > 3) s3 = ldA(B16, B32, i3);
            if (nv > 0) *(f16x8*)((char*)Alds + ((((i0 >> 5) * ROWB + (i0 & 31) * 16)) ^ (((i0 >> 5) & 7) << 4))) = s0;
            if (nv > 1) *(f16x8*)((char*)Alds + ((((i1 >> 5) * ROWB + (i1 & 31) * 16)) ^ (((i1 >> 5) & 7) << 4))) = s1;
            if (nv > 2) *(f16x8*)((char*)Alds + ((((i2 >> 5) * ROWB + (i2 & 31) * 16)) ^ (((i2 >> 5) & 7) << 4))) = s2;
            if (nv > 3) *(f16x8*)((char*)Alds + ((((i3 >> 5) * ROWB + (i3 & 31) * 16)) ^ (((i3 >> 5) & 7) << 4))) = s3;
        }
        if (TOTC % NOUT) {              // remainder (NOUT=384 case)
            const int idx = tid + NSTG * NOUT;
            if (idx < TOTC) {
                f16x8 v = ldA(B16, B32, idx);
                const int r = idx >> 5, c = idx & 31;
                *(f16x8*)((char*)Alds + ((r * ROWB + c * 16) ^ ((r & 7) << 4))) = v;
            }
        }
    };

    // issue B prefetch for steps 0..3 BEFORE staging (overlaps A latency)
    LDB(pa0, pa1, pa2, pa3, 0)
    LDB(pb0, pb1, pb2, pb3, 1)
    LDB(pc0, pc1, pc2, pc3, 2)
    LDB(pd0, pd1, pd2, pd3, 3)

    stage(A1, A1f);
    __syncthreads();

    f32x4 acc[4][4];
#pragma unroll
    for (int i = 0; i < 4; i++)
#pragma unroll
        for (int j = 0; j < 4; j++) acc[i][j] = 0.f;

#define MSTEP(OFF, P0, P1, P2, P3)                                             \
    {                                                                          \
        const char* ap_ = (const char*)Alds + (OFF);                           \
        f16x8 a0_ = *(const f16x8*)(ap_);                                      \
        f16x8 a1_ = *(const f16x8*)(ap_ + 16 * ROWB);                          \
        f16x8 a2_ = *(const f16x8*)(ap_ + 32 * ROWB);                          \
        f16x8 a3_ = *(const f16x8*)(ap_ + 48 * ROWB);                          \
        acc[0][0] = __builtin_amdgcn_mfma_f32_16x16x32_f16(a0_, P0, acc[0][0], 0, 0, 0); \
        acc[0][1] = __builtin_amdgcn_mfma_f32_16x16x32_f16(a0_, P1, acc[0][1], 0, 0, 0); \
        acc[0][2] = __builtin_amdgcn_mfma_f32_16x16x32_f16(a0_, P2, acc[0][2], 0, 0, 0); \
        acc[0][3] = __builtin_amdgcn_mfma_f32_16x16x32_f16(a0_, P3, acc[0][3], 0, 0, 0); \
        acc[1][0] = __builtin_amdgcn_mfma_f32_16x16x32_f16(a1_, P0, acc[1][0], 0, 0, 0); \
        acc[1][1] = __builtin_amdgcn_mfma_f32_16x16x32_f16(a1_, P1, acc[1][1], 0, 0, 0); \
        acc[1][2] = __builtin_amdgcn_mfma_f32_16x16x32_f16(a1_, P2, acc[1][2], 0, 0, 0); \
        acc[1][3] = __builtin_amdgcn_mfma_f32_16x16x32_f16(a1_, P3, acc[1][3], 0, 0, 0); \
        acc[2][0] = __builtin_amdgcn_mfma_f32_16x16x32_f16(a2_, P0, acc[2][0], 0, 0, 0); \
        acc[2][1] = __builtin_amdgcn_mfma_f32_16x16x32_f16(a2_, P1, acc[2][1], 0, 0, 0); \
        acc[2][2] = __builtin_amdgcn_mfma_f32_16x16x32_f16(a2_, P2, acc[2][2], 0, 0, 0); \
        acc[2][3] = __builtin_amdgcn_mfma_f32_16x16x32_f16(a2_, P3, acc[2][3], 0, 0, 0); \
        acc[3][0] = __builtin_amdgcn_mfma_f32_16x16x32_f16(a3_, P0, acc[3][0], 0, 0, 0); \
        acc[3][1] = __builtin_amdgcn_mfma_f32_16x16x32_f16(a3_, P1, acc[3][1], 0, 0, 0); \
        acc[3][2] = __builtin_amdgcn_mfma_f32_16x16x32_f16(a3_, P2, acc[3][2], 0, 0, 0); \
        acc[3][3] = __builtin_amdgcn_mfma_f32_16x16x32_f16(a3_, P3, acc[3][3], 0, 0, 0); \
    }

    const int swz = (r16 & 7) << 4;
#pragma unroll
    for (int h = 0; h < HALVES; ++h) {
        if (h > 0) {
            __syncthreads();            // all waves done reading half 0
            stage(A2, nullptr);
            __syncthreads();
        }
        int au = r16 * ROWB + kc * 16;
#pragma unroll
        for (int tt = 0; tt < 8; tt += 4) {
            const int t = h * 8 + tt;   // global K-step for B indexing
            MSTEP((au      ) ^ swz, pa0, pa1, pa2, pa3)
            if (t + 4 < NT) LDB(pa0, pa1, pa2, pa3, t + 4)
            MSTEP((au +  64) ^ swz, pb0, pb1, pb2, pb3)
            if (t + 5 < NT) LDB(pb0, pb1, pb2, pb3, t + 5)
            MSTEP((au + 128) ^ swz, pc0, pc1, pc2, pc3)
            if (t + 6 < NT) LDB(pc0, pc1, pc2, pc3, t + 6)
            MSTEP((au + 192) ^ swz, pd0, pd1, pd2, pd3)
            if (t + 7 < NT) LDB(pd0, pd1, pd2, pd3, t + 7)
            au += 256;
        }
    }
#undef LDB
#undef MSTEP

    // epilogue: C[m = quad*4+reg][n = lane&15] per 16x16 tile (m89 layout)
    const int rbase = (lane >> 4) * 4;
    const int ncol  = lane & 15;
    if constexpr (BUN == 2) {
        // fp32 LDS C-tile -> per-(row,bundle) Q^T transform -> d_out direct
        __syncthreads();                // all waves done reading Alds
        float* Cl = (float*)Alds;
        constexpr int CS4 = NOUT + 8;
#pragma unroll
        for (int nt = 0; nt < 4; nt++) {
            const int n = wave * 64 + nt * 16 + ncol;
            const float bs = bias[n];
#pragma unroll
            for (int mt = 0; mt < 4; mt++)
#pragma unroll
                for (int i = 0; i < 4; i++)
                    Cl[(mt * 16 + rbase + i) * CS4 + n] = acc[mt][nt][i] + bs;
        }
        __syncthreads();
#pragma unroll
        for (int it = 0; it < 4096 / NOUT; it++) {
            const int item = tid + it * NOUT;
            const int row = item >> 6, b = item & 63;
            float4 v = *(const float4*)&Cl[row * CS4 + b * 4];
            float Q[4][4];
            make_Q(nrq + (size_t)(m0 + row) * 384 + b * 6, Q);
            float4 o;
            o.x = Q[0][0]*v.x + Q[1][0]*v.y + Q[2][0]*v.z + Q[3][0]*v.w;
            o.y = Q[0][1]*v.x + Q[1][1]*v.y + Q[2][1]*v.z + Q[3][1]*v.w;
            o.z = Q[0][2]*v.x + Q[1][2]*v.y + Q[2][2]*v.z + Q[3][2]*v.w;
            o.w = Q[0][3]*v.x + Q[1][3]*v.y + Q[2][3]*v.z + Q[3][3]*v.w;
            *(float4*)(outf + (size_t)(m0 + row) * 256 + b * 4) = o;
        }
    } else {
        // W16: coalesced path via padded fp16 LDS C-tile
        __syncthreads();                // all waves done reading Alds
        constexpr int CPRN = NOUT / 8;  // 16B chunks per C row
        constexpr int CPT  = 64 * CPRN / NOUT;   // chunks per thread (= 8)
        f16x8 res[CPT];
        if constexpr (RESA) {
#pragma unroll
            for (int k2 = 0; k2 < CPT; k2++) {
                const int c = tid + k2 * NOUT;
                const int row = c / CPRN, col = c - row * CPRN;
                res[k2] = *(const f16x8*)(A1 + (size_t)(m0 + row) * 256 + col * 8);
            }
        }
#pragma unroll
        for (int nt = 0; nt < 4; nt++) {
            const int n = wave * 64 + nt * 16 + ncol;
            const float bs = bias[n];
#pragma unroll
            for (int mt = 0; mt < 4; mt++) {
#pragma unroll
                for (int i = 0; i < 4; i++) {
                    const int mr = mt * 16 + rbase + i;
                    float v = acc[mt][nt][i] + bs;
                    if (ACT) v = gelu_f(v);
                    Alds[mr * CTS + n] = (_Float16)v;
                }
            }
        }
        __syncthreads();
#pragma unroll
        for (int k2 = 0; k2 < CPT; k2++) {
            const int c = tid + k2 * NOUT;
            const int row = c / CPRN, col = c - row * CPRN;
            f16x8 v = *(const f16x8*)&Alds[row * CTS + col * 8];
            if constexpr (RESA) v = v + res[k2];
            *(f16x8*)(C16 + (size_t)(m0 + row) * NOUT + col * 8) = v;
        }
        if constexpr (BUN == 1) {
            // fused bundle<false>: vf16[n, b*4+i] = sum_j Q[i][j] x[n, b*4+j]
            // Q-params read straight from the LDS C-tile (this block's rows)
            constexpr int NIT = (4096 + NOUT - 1) / NOUT;
#pragma unroll
            for (int it = 0; it < NIT; it++) {
                const int item = tid + it * NOUT;
                if (item < 4096) {
                    const int row = item >> 6, b = item & 63;
                    float4 xv = *(const float4*)(xin + (size_t)(m0 + row) * 256 + b * 4);
                    float Q[4][4];
                    make_Q(&Alds[row * CTS + b * 6], Q);
                    f16x4 o = {
                        (_Float16)(Q[0][0]*xv.x + Q[0][1]*xv.y + Q[0][2]*xv.z + Q[0][3]*xv.w),
                        (_Float16)(Q[1][0]*xv.x + Q[1][1]*xv.y + Q[1][2]*xv.z + Q[1][3]*xv.w),
                        (_Float16)(Q[2][0]*xv.x + Q[2][1]*xv.y + Q[2][2]*xv.z + Q[2][3]*xv.w),
                        (_Float16)(Q[3][0]*xv.x + Q[3][1]*xv.y + Q[3][2]*xv.z + Q[3][3]*xv.w) };
                    *(f16x4*)(vf16 + (size_t)(m0 + row) * 256 + b * 4) = o;
                }
            }
        }
    }
}

// ---------------------------------------------------------------------------
// Weight pack: fp32 W[k][n] (k-major, row stride NOUT) -> fragment-ordered
// fp16 chunks. Chunk cid = ((wn*NT + t)*4 + q)*64 + l holds 8 halfs:
// value[j] = W[t*32 + (l>>4)*8 + j][wn*64 + q*16 + (l&15)].
// DUAL: k >= 256 reads W2[k-256][n].
// ---------------------------------------------------------------------------
template<int NOUT, int KTOT, bool DUAL>
__global__ __launch_bounds__(256) void pack_k(
    const float* __restrict__ W1, const float* __restrict__ W2,
    _Float16* __restrict__ Bp)
{
    constexpr int NT = KTOT / 32;
    const int cid = blockIdx.x * 256 + threadIdx.x;
    if (cid >= NOUT * KTOT / 8) return;
    const int l  = cid & 63;
    const int q  = (cid >> 6) & 3;
    const int c2 = cid >> 8;            // wn*NT + t
    const int t  = c2 & (NT - 1);
    const int wn = c2 / NT;
    const int n  = wn * 64 + q * 16 + (l & 15);
    const int k0 = t * 32 + (l >> 4) * 8;
    f16x8 v;
#pragma unroll
    for (int j = 0; j < 8; j++) {
        const int k = k0 + j;
        float w = (DUAL && k >= 256) ? W2[(size_t)(k - 256) * NOUT + n]
                                     : W1[(size_t)k * NOUT + n];
        v[j] = (_Float16)w;
    }
    *(f16x8*)(Bp + (size_t)cid * 8) = v;
}

// ---------------------------------------------------------------------------
__global__ void zero_k(float* __restrict__ p, size_t n)
{
    size_t i = (size_t)blockIdx.x * blockDim.x + threadIdx.x;
    float4* p4 = (float4*)p;
    size_t n4 = n >> 2;
    for (size_t j = i; j < n4; j += (size_t)gridDim.x * blockDim.x)
        p4[j] = make_float4(0.f, 0.f, 0.f, 0.f);
}

__global__ void bcomb_k(const float* __restrict__ a, const float* __restrict__ b,
                        float* __restrict__ o)
{
    int i = blockIdx.x * 256 + threadIdx.x;
    if (i < 512) o[i] = a[i] + b[i];
}

// ---------------------------------------------------------------------------
// CSR build: histogram of dst, exclusive scan, cursor fill
// ---------------------------------------------------------------------------
__global__ __launch_bounds__(256) void hist_k(const int* __restrict__ ei, int* __restrict__ deg)
{
    int e = blockIdx.x * 256 + threadIdx.x;
    if (e < NEDGE) atomicAdd(&deg[ei[NEDGE + e]], 1);
}

__global__ __launch_bounds__(1024) void scan_k(
    const int* __restrict__ deg, int* __restrict__ off, int* __restrict__ cursor)
{
    __shared__ int sh[1024];
    const int tid = threadIdx.x;
    const int base = tid * 64;
    int s = 0;
#pragma unroll 8
    for (int i = 0; i < 64; i++) s += deg[base + i];
    const int mysum = s;
    sh[tid] = s;
    __syncthreads();
    for (int ofs = 1; ofs < 1024; ofs <<= 1) {
        int v = (tid >= ofs) ? sh[tid - ofs] : 0;
        __syncthreads();
        sh[tid] += v;
        __syncthreads();
    }
    int running = sh[tid] - mysum;
    for (int i = 0; i < 64; i++) {
        off[base + i] = running;
        cursor[base + i] = running;
        running += deg[base + i];
    }
    if (tid == 1023) off[NN] = running;
}

__global__ __launch_bounds__(256) void fill_k(
    const int* __restrict__ ei, int* __restrict__ cursor, int* __restrict__ csr)
{
    int e = blockIdx.x * 256 + threadIdx.x;
    if (e < NEDGE) {
        int d = ei[NEDGE + e];
        int pos = atomicAdd(&cursor[d], 1);
        csr[pos] = ei[e];   // src
    }
}

// ---------------------------------------------------------------------------
// Gather segment-sum over fp16 h: fp32 accum, fp16 out. 4 rows in flight.
// ---------------------------------------------------------------------------
__global__ __launch_bounds__(256) void gather16_k(
    const _Float16* __restrict__ h, const int* __restrict__ off,
    const int* __restrict__ csr, _Float16* __restrict__ agg)
{
    const int lane = threadIdx.x & 63;
    const int n = blockIdx.x * 4 + (threadIdx.x >> 6);
    const int s0 = off[n], s1 = off[n + 1];
    float a0 = 0.f, a1 = 0.f, a2 = 0.f, a3 = 0.f;
    int j = s0;
    for (; j + 3 < s1; j += 4) {
        const int i0 = csr[j], i1 = csr[j + 1], i2 = csr[j + 2], i3 = csr[j + 3];
        f16x4 v0 = ((const f16x4*)(h + (size_t)i0 * CH))[lane];
        f16x4 v1 = ((const f16x4*)(h + (size_t)i1 * CH))[lane];
        f16x4 v2 = ((const f16x4*)(h + (size_t)i2 * CH))[lane];
        f16x4 v3 = ((const f16x4*)(h + (size_t)i3 * CH))[lane];
        a0 += (float)v0[0] + (float)v1[0] + (float)v2[0] + (float)v3[0];
        a1 += (float)v0[1] + (float)v1[1] + (float)v2[1] + (float)v3[1];
        a2 += (float)v0[2] + (float)v1[2] + (float)v2[2] + (float)v3[2];
        a3 += (float)v0[3] + (float)v1[3] + (float)v2[3] + (float)v3[3];
    }
    for (; j < s1; j++) {
        f16x4 va = ((const f16x4*)(h + (size_t)csr[j] * CH))[lane];
        a0 += (float)va[0]; a1 += (float)va[1]; a2 += (float)va[2]; a3 += (float)va[3];
    }
    f16x4 o = { (_Float16)a0, (_Float16)a1, (_Float16)a2, (_Float16)a3 };
    ((f16x4*)(agg + (size_t)n * CH))[lane] = o;
}

// ---------------------------------------------------------------------------
// Spectral kernels (vf is fp16 now)
// ---------------------------------------------------------------------------
__global__ __launch_bounds__(256) void spec_proj_k(
    const _Float16* __restrict__ v, const float* __restrict__ eigvec, float* __restrict__ hs)
{
    const int g = blockIdx.x;
    const int nbase = g * NPG + blockIdx.y * 128;
    __shared__ float evs[16][32];
    float acc[32];
#pragma unroll
    for (int k = 0; k < 32; k++) acc[k] = 0.f;
    for (int nt = 0; nt < 128; nt += 16) {
        __syncthreads();
        for (int i = threadIdx.x; i < 512; i += 256) {
            int nn = i >> 5, kk = i & 31;
            evs[nn][kk] = eigvec[(size_t)(nbase + nt + nn) * KEIG + kk];
        }
        __syncthreads();
#pragma unroll 4
        for (int nn = 0; nn < 16; nn++) {
            float hv = (float)v[(size_t)(nbase + nt + nn) * CH + threadIdx.x];
#pragma unroll
            for (int k = 0; k < 32; k++) acc[k] += evs[nn][k] * hv;
        }
    }
    float* o = hs + (size_t)g * KEIG * CH + threadIdx.x;
#pragma unroll
    for (int k = 0; k < 32; k++) atomicAdd(o + k * CH, acc[k]);
}

// out16[g,n,d] = sum_v ev[g,n,v] * hs[g,v,d] * exp(-eigval[g,v]*taus[d>>2])
// (spec_scale fused into the hs load)
__global__ __launch_bounds__(256) void spec_reproj16_k(
    const float* __restrict__ eigvec, const float* __restrict__ hs,
    const float* __restrict__ eigval, const float* __restrict__ taus,
    _Float16* __restrict__ out16)
{
    const int g = blockIdx.x >> 4;
    const int nbase = g * NPG + (blockIdx.x & 15) * 64;
    const float tau = taus[threadIdx.x >> 2];
    float hsr[32];
    const float* hg = hs + (size_t)g * KEIG * CH + threadIdx.x;
#pragma unroll
    for (int k = 0; k < 32; k++)
        hsr[k] = hg[k * CH] * expf(-eigval[g * KEIG + k] * tau);
    __shared__ float evs[64][32];
    for (int i = threadIdx.x; i < 2048; i += 256) {
        int nn = i >> 5, kk = i & 31;
        evs[nn][kk] = eigvec[(size_t)(nbase + nn) * KEIG + kk];
    }
    __syncthreads();
    for (int nn = 0; nn < 64; nn++) {
        float a = 0.f;
#pragma unroll
        for (int k = 0; k < 32; k++) a += evs[nn][k] * hsr[k];
        out16[(size_t)(nbase + nn) * CH + threadIdx.x] = (_Float16)a;
    }
}

// ---------------------------------------------------------------------------
extern "C" void kernel_launch(void* const* d_in, const int* in_sizes, int n_in,
                              void* d_out, int out_size, void* d_ws, size_t ws_size,
                              hipStream_t stream)
{
    const float* x      = (const float*)d_in[0];
    const float* eigvec = (const float*)d_in[1];
    const float* eigval = (const float*)d_in[2];
    const float* taus   = (const float*)d_in[3];
    const float* enc_w  = (const float*)d_in[4];
    const float* enc_b  = (const float*)d_in[5];
    const float* self_w = (const float*)d_in[6];
    const float* self_b = (const float*)d_in[7];
    const float* nb_w   = (const float*)d_in[8];
    const float* nb_b   = (const float*)d_in[9];
    const float* dec_w  = (const float*)d_in[10];
    const float* dec_b  = (const float*)d_in[11];
    const float* lin_w  = (const float*)d_in[12];
    const float* lin_b  = (const float*)d_in[13];
    const int*   ei     = (const int*)d_in[14];
    (void)in_sizes; (void)n_in; (void)out_size; (void)ws_size;

    float* ws = (float*)d_ws;
    // Stream-ordered lifetimes (float-slot offsets). cvt16/x16, bundle_k,
    // vf1(fp32) and h3 are GONE (fused into GEMM epilogues, R9):
    //  [0,        524288)   hs [64,32,256] fp32 (was x16 region; free)
    //  [8388608, 16777216)  h0
    //  [16777216,25165824)  h1 -> vf16 [NN,256] fp16 (h1 dead after L2)
    //  [25165824,33554432)  agg          -> nr16 part
    //  [33554432,34275329)  CSR ints     -> nr16 part
    //  [25165824,37748736)  nr16 [NN,384] fp16 (dec out; agg+CSR dead)
    //  [37748752,37995024)  packed weights + lbias
    //  [37995024,46383632)  h2 [NN,256] fp16
    // high-water: 46,383,632 fl = 185.5 MB (unchanged)
    _Float16* h0  = (_Float16*)(ws + 8388608);
    _Float16* h1  = (_Float16*)(ws + 16777216);
    _Float16* agg = (_Float16*)(ws + 25165824);
    int* ibase  = (int*)(ws + 33554432);
    int* deg    = ibase;                 // NN
    int* off    = ibase + 65536;         // NN+1
    int* cursor = ibase + 131073;        // NN
    int* csr    = ibase + 196609;        // NEDGE (ends slot 34275329)
    _Float16* nr16 = (_Float16*)(ws + 25165824);  // [NN,384] fp16
    float* wb = ws + 37748752;
    _Float16* enc16 = (_Float16*)(wb);            // packed [256x256]
    _Float16* l1w   = (_Float16*)(wb + 32768);    // packed [256x512]
    _Float16* l2w   = (_Float16*)(wb + 98304);    // packed [256x512]
    _Float16* dec16 = (_Float16*)(wb + 163840);   // packed [384x256]
    _Float16* lin16 = (_Float16*)(wb + 212992);   // packed [256x256]
    float* lbias = wb + 245760;                   // [2,256] (ends wb+246272)
    _Float16* h2 = (_Float16*)(ws + 37995024);    // [NN,256] fp16
    _Float16* vf16 = (_Float16*)(ws + 16777216);  // [NN,256] fp16 (h1 dead)
    float* hs  = ws;                              // [64,32,256] fp32

    dim3 blk(256);

    // ---- prep ----
    pack_k<256, 256, false><<<32, blk, 0, stream>>>(enc_w, nullptr, enc16);
    pack_k<256, 512, true ><<<64, blk, 0, stream>>>(self_w,         nb_w,         l1w);
    pack_k<256, 512, true ><<<64, blk, 0, stream>>>(self_w + 65536, nb_w + 65536, l2w);
    pack_k<384, 256, false><<<48, blk, 0, stream>>>(dec_w, nullptr, dec16);
    pack_k<256, 256, false><<<32, blk, 0, stream>>>(lin_w, nullptr, lin16);
    bcomb_k<<<2, blk, 0, stream>>>(self_b, nb_b, lbias);
    zero_k<<<64, blk, 0, stream>>>((float*)deg, (size_t)NN);
    hist_k<<<NEDGE / 256, blk, 0, stream>>>(ei, deg);
    scan_k<<<1, 1024, 0, stream>>>(deg, off, cursor);
    fill_k<<<NEDGE / 256, blk, 0, stream>>>(ei, cursor, csr);

    // ---- h0 = gelu(x @ enc_w + enc_b)  (A32: stages fp32 x directly) ----
    mgemm_k<256, 256, false, true, false, true, true, 0><<<1024, blk, 0, stream>>>(
        nullptr, nullptr, x, enc16, enc_b, h0, nullptr, nullptr, nullptr, nullptr);

    // ---- GNN layer 1: h1 = gelu([h0,agg]@W + b) + h0 ----
    gather16_k<<<NN / 4, blk, 0, stream>>>(h0, off, csr, agg);
    mgemm_k<256, 512, true, true, true, true, false, 0><<<1024, blk, 0, stream>>>(
        h0, agg, nullptr, l1w, lbias, h1, nullptr, nullptr, nullptr, nullptr);

    // ---- GNN layer 2: h0 = gelu([h1,agg]@W + b) + h1 ----
    gather16_k<<<NN / 4, blk, 0, stream>>>(h1, off, csr, agg);
    mgemm_k<256, 512, true, true, true, true, false, 0><<<1024, blk, 0, stream>>>(
        h1, agg, nullptr, l2w, lbias + 256, h0, nullptr, nullptr, nullptr, nullptr);

    // ---- node_rep = h0 @ dec_w + dec_b  + FUSED vf16 = Q . x ----
    mgemm_k<384, 256, false, false, false, true, false, 1><<<1024, dim3(384), 0, stream>>>(
        h0, nullptr, nullptr, dec16, dec_b, nr16, x, vf16, nullptr, nullptr);

    // ---- spectral filter (scale fused into reproj) ----
    zero_k<<<512, blk, 0, stream>>>(hs, (size_t)GG * KEIG * CH);
    spec_proj_k<<<dim3(GG, 8), blk, 0, stream>>>(vf16, eigvec, hs);
    spec_reproj16_k<<<GG * 16, blk, 0, stream>>>(eigvec, hs, eigval, taus, h2);

    // ---- out = Q^T . (h2 @ lin_w + lin_b)  (FUSED, fp32 tile, direct) ----
    mgemm_k<256, 256, false, false, false, false, false, 2><<<1024, blk, 0, stream>>>(
        h2, nullptr, nullptr, lin16, lin_b, nullptr, nullptr, nullptr, nr16, (float*)d_out);
}

// Round 10
// 621.817 us; speedup vs baseline: 1.1298x; 1.0251x over previous
//
#include <hip/hip_runtime.h>
#include <math.h>

// Problem constants
#define NN      65536
#define GG      64
#define NPG     1024
#define KEIG    32
#define NBUN    64
#define BDIM    4
#define CH      256        // IN_CH == GNN_DIM == NB*BD
#define NBP     384
#define NEDGE   524288

using f16x8 = __attribute__((ext_vector_type(8))) _Float16;
using f16x4 = __attribute__((ext_vector_type(4))) _Float16;
using f32x4 = __attribute__((ext_vector_type(4))) float;

__device__ __forceinline__ float gelu_f(float x) {
    return 0.5f * x * (1.0f + erff(x * 0.70710678118654752440f));
}

// ---------------------------------------------------------------------------
// Householder Q from 6 fp16 params (BD=4: 3 reflectors)
// ---------------------------------------------------------------------------
__device__ __forceinline__ void make_Q(const _Float16* __restrict__ p, float Q[4][4])
{
#pragma unroll
    for (int i = 0; i < 4; i++)
#pragma unroll
        for (int j = 0; j < 4; j++) Q[i][j] = (i == j) ? 1.f : 0.f;
    int idx = 0;
#pragma unroll
    for (int j = 0; j < 3; j++) {
        float v[4] = {0.f, 0.f, 0.f, 0.f};
        v[j] = 1.f;
#pragma unroll
        for (int t = 0; t < 4; t++)
            if (t > j) v[t] = (float)p[idx + t - (j + 1)];
        idx += 3 - j;
        float nrm = v[0]*v[0] + v[1]*v[1] + v[2]*v[2] + v[3]*v[3];
        float s = 2.f / nrm;
#pragma unroll
        for (int i = 0; i < 4; i++) {
            float qv = Q[i][0]*v[0] + Q[i][1]*v[1] + Q[i][2]*v[2] + Q[i][3]*v[3];
            float t0 = s * qv;
#pragma unroll
            for (int c = 0; c < 4; c++) Q[i][c] -= t0 * v[c];
        }
    }
}

// ---------------------------------------------------------------------------
// fp16 MFMA GEMM (proven: all-coalesced loads R5, coalesced W16 epilogue R6,
// split-K 33KB staging R7/R8, fused bundle epilogues R9).
// R9 counter finding: DUAL WRITE=62.5MB vs 32.8 logical, FETCH 64 vs 37 (R6)
// -> +28MB EACH WAY of scratch spill. Cause: in-loop B prefetch loaded steps
// 8-11 BEFORE the half boundary, so 4 prefetch sets (64 VGPR) stayed live
// ACROSS the mid-loop A2 restage (stage + 2 barriers) -> allocator spilled
// them. R10: drain the B queue at the half boundary (prefetch only within the
// current half), issue the next half's 4 LDB sets AFTER the restage. K=256
// kernels (HALVES=1) are codegen-identical.
//  A32: stage A directly from fp32 (kills the cvt16 pass).
//  BUN==1 (dec): epilogue also computes vf16 = Q . x from the LDS C-tile.
//  BUN==2 (lin): fp32 LDS C-tile + per-(row,bundle) Q^T -> d_out direct.
// DUAL: A = concat_k(A1, A2), KTOT=512.  RESA: + A1[m,n] residual (NOUT==256).
// Outputs disjoint from ALL inputs (graph-replay safety).
// ---------------------------------------------------------------------------
template<int NOUT, int KTOT, bool DUAL, bool ACT, bool RESA, bool W16, bool A32, int BUN>
__global__ __launch_bounds__(NOUT, 3) void mgemm_k(
    const _Float16* __restrict__ A1, const _Float16* __restrict__ A2,
    const float* __restrict__ A1f, const _Float16* __restrict__ Bp,
    const float* __restrict__ bias, _Float16* __restrict__ C16,
    const float* __restrict__ xin, _Float16* __restrict__ vf16,
    const _Float16* __restrict__ nrq, float* __restrict__ outf)
{
    constexpr int NT   = KTOT / 32;     // total K-steps (8 or 16)
    constexpr int HALVES = KTOT / 256;  // 1 or 2 half-panels of K=256
    constexpr int ROWB = 512;           // LDS bytes per A row (K=256 half)
    constexpr int CPR  = 32;            // 16B chunks per A row (half)
    constexpr int TOTC = 64 * CPR;      // 2048 chunks per half-panel
    constexpr int NSTG = TOTC / NOUT;   // full stage iters per thread
    constexpr int CTS  = NOUT + 8;      // padded C-tile row stride (halfs)
    constexpr int AH   = 64 * 256;      // A half-panel halfs (32 KB)
    constexpr int W16H = W16 ? 64 * CTS : 0;
    constexpr int B2H  = (BUN == 2) ? 64 * CTS * 2 : 0;   // fp32 tile as halfs
    constexpr int LDSH = (AH > W16H) ? ((AH > B2H) ? AH : B2H)
                                     : ((W16H > B2H) ? W16H : B2H);
    __shared__ _Float16 Alds[LDSH];

    const int tid  = threadIdx.x;
    const int lane = tid & 63;
    const int wave = tid >> 6;          // wave owns cols wave*64..wave*64+63
    const int m0   = blockIdx.x * 64;   // block's 64 A rows

    const int r16 = lane & 15;          // fragment row / col within 16
    const int kc  = lane >> 4;          // k-chunk 0..3

    // B packed: chunk((wn*NT + t)*4 + q), lane-contiguous 16B each
    const _Float16* bpp = Bp + ((size_t)wave * NT * 2048) + lane * 8;

    f16x8 pa0, pa1, pa2, pa3, pb0, pb1, pb2, pb3;
    f16x8 pc0, pc1, pc2, pc3, pd0, pd1, pd2, pd3;

#define LDB(P0, P1, P2, P3, T)                                                 \
    {                                                                          \
        const _Float16* bq_ = bpp + (size_t)(T) * 2048;                        \
        P0 = *(const f16x8*)(bq_);                                             \
        P1 = *(const f16x8*)(bq_ + 512);                                       \
        P2 = *(const f16x8*)(bq_ + 1024);                                      \
        P3 = *(const f16x8*)(bq_ + 1536);                                      \
    }

    // coalesced A-chunk load (fp16 direct, or fp32 + inline cvt when A32)
    auto ldA = [&](const _Float16* B16, const float* B32, int idx) -> f16x8 {
        const size_t off = (size_t)(m0 + (idx >> 5)) * 256 + (idx & 31) * 8;
        if constexpr (A32) {
            float4 lo = *(const float4*)(B32 + off);
            float4 hi = *(const float4*)(B32 + off + 4);
            f16x8 r = { (_Float16)lo.x, (_Float16)lo.y, (_Float16)lo.z, (_Float16)lo.w,
                        (_Float16)hi.x, (_Float16)hi.y, (_Float16)hi.z, (_Float16)hi.w };
            return r;
        } else {
            return *(const f16x8*)(B16 + off);
        }
    };

    // stage one 64x256 half-panel: groups of 4 coalesced loads -> regs ->
    // swizzled LDS (16 VGPRs of staging state)
    auto stage = [&](const _Float16* B16, const float* B32) {
#pragma unroll
        for (int j0 = 0; j0 < NSTG; j0 += 4) {
            f16x8 s0, s1, s2, s3;
            const int nv = (NSTG - j0 >= 4) ? 4 : (NSTG - j0);
            int i0 = tid + (j0 + 0) * NOUT;
            int i1 = tid + (j0 + 1) * NOUT;
            int i2 = tid + (j0 + 2) * NOUT;
            int i3 = tid + (j0 + 3) * NOUT;
            if (nv > 0) s0 = ldA(B16, B32, i0);
            if (nv > 1) s1 = ldA(B16, B32, i1);
            if (nv > 2) s2 = ldA(B16, B32, i2);
            if (nv > 3) s3 = ldA(B16, B32, i3);
            if (nv > 0) *(f16x8*)((char*)Alds + ((((i0 >> 5) * ROWB + (i0 & 31) * 16)) ^ (((i0 >> 5) & 7) << 4))) = s0;
            if (nv > 1) *(f16x8*)((char*)Alds + ((((i1 >> 5) * ROWB + (i1 & 31) * 16)) ^ (((i1 >> 5) & 7) << 4))) = s1;
            if (nv > 2) *(f16x8*)((char*)Alds + ((((i2 >> 5) * ROWB + (i2 & 31) * 16)) ^ (((i2 >> 5) & 7) << 4))) = s2;
            if (nv > 3) *(f16x8*)((char*)Alds + ((((i3 >> 5) * ROWB + (i3 & 31) * 16)) ^ (((i3 >> 5) & 7) << 4))) = s3;
        }
        if (TOTC % NOUT) {              // remainder (NOUT=384 case)
            const int idx = tid + NSTG * NOUT;
            if (idx < TOTC) {
                f16x8 v = ldA(B16, B32, idx);
                const int r = idx >> 5, c = idx & 31;
                *(f16x8*)((char*)Alds + ((r * ROWB + c * 16) ^ ((r & 7) << 4))) = v;
            }
        }
    };

    // issue B prefetch for steps 0..3 BEFORE staging (overlaps A latency;
    // proven spill-free across a single pre-loop stage in R6)
    LDB(pa0, pa1, pa2, pa3, 0)
    LDB(pb0, pb1, pb2, pb3, 1)
    LDB(pc0, pc1, pc2, pc3, 2)
    LDB(pd0, pd1, pd2, pd3, 3)

    stage(A1, A1f);
    __syncthreads();

    f32x4 acc[4][4];
#pragma unroll
    for (int i = 0; i < 4; i++)
#pragma unroll
        for (int j = 0; j < 4; j++) acc[i][j] = 0.f;

#define MSTEP(OFF, P0, P1, P2, P3)                                             \
    {                                                                          \
        const char* ap_ = (const char*)Alds + (OFF);                           \
        f16x8 a0_ = *(const f16x8*)(ap_);                                      \
        f16x8 a1_ = *(const f16x8*)(ap_ + 16 * ROWB);                          \
        f16x8 a2_ = *(const f16x8*)(ap_ + 32 * ROWB);                          \
        f16x8 a3_ = *(const f16x8*)(ap_ + 48 * ROWB);                          \
        acc[0][0] = __builtin_amdgcn_mfma_f32_16x16x32_f16(a0_, P0, acc[0][0], 0, 0, 0); \
        acc[0][1] = __builtin_amdgcn_mfma_f32_16x16x32_f16(a0_, P1, acc[0][1], 0, 0, 0); \
        acc[0][2] = __builtin_amdgcn_mfma_f32_16x16x32_f16(a0_, P2, acc[0][2], 0, 0, 0); \
        acc[0][3] = __builtin_amdgcn_mfma_f32_16x16x32_f16(a0_, P3, acc[0][3], 0, 0, 0); \
        acc[1][0] = __builtin_amdgcn_mfma_f32_16x16x32_f16(a1_, P0, acc[1][0], 0, 0, 0); \
        acc[1][1] = __builtin_amdgcn_mfma_f32_16x16x32_f16(a1_, P1, acc[1][1], 0, 0, 0); \
        acc[1][2] = __builtin_amdgcn_mfma_f32_16x16x32_f16(a1_, P2, acc[1][2], 0, 0, 0); \
        acc[1][3] = __builtin_amdgcn_mfma_f32_16x16x32_f16(a1_, P3, acc[1][3], 0, 0, 0); \
        acc[2][0] = __builtin_amdgcn_mfma_f32_16x16x32_f16(a2_, P0, acc[2][0], 0, 0, 0); \
        acc[2][1] = __builtin_amdgcn_mfma_f32_16x16x32_f16(a2_, P1, acc[2][1], 0, 0, 0); \
        acc[2][2] = __builtin_amdgcn_mfma_f32_16x16x32_f16(a2_, P2, acc[2][2], 0, 0, 0); \
        acc[2][3] = __builtin_amdgcn_mfma_f32_16x16x32_f16(a2_, P3, acc[2][3], 0, 0, 0); \
        acc[3][0] = __builtin_amdgcn_mfma_f32_16x16x32_f16(a3_, P0, acc[3][0], 0, 0, 0); \
        acc[3][1] = __builtin_amdgcn_mfma_f32_16x16x32_f16(a3_, P1, acc[3][1], 0, 0, 0); \
        acc[3][2] = __builtin_amdgcn_mfma_f32_16x16x32_f16(a3_, P2, acc[3][2], 0, 0, 0); \
        acc[3][3] = __builtin_amdgcn_mfma_f32_16x16x32_f16(a3_, P3, acc[3][3], 0, 0, 0); \
    }

    const int swz = (r16 & 7) << 4;
#pragma unroll
    for (int h = 0; h < HALVES; ++h) {
        if (h > 0) {
            __syncthreads();            // all waves done reading half 0
            stage(A2, nullptr);
            __syncthreads();
            // refill B queue AFTER the restage: no B regs live across it
            LDB(pa0, pa1, pa2, pa3, 8)
            LDB(pb0, pb1, pb2, pb3, 9)
            LDB(pc0, pc1, pc2, pc3, 10)
            LDB(pd0, pd1, pd2, pd3, 11)
        }
        int au = r16 * ROWB + kc * 16;
#pragma unroll
        for (int tt = 0; tt < 8; tt += 4) {
            const int t = h * 8 + tt;   // global K-step for B indexing
            MSTEP((au      ) ^ swz, pa0, pa1, pa2, pa3)
            if (tt + 4 < 8) LDB(pa0, pa1, pa2, pa3, t + 4)
            MSTEP((au +  64) ^ swz, pb0, pb1, pb2, pb3)
            if (tt + 5 < 8) LDB(pb0, pb1, pb2, pb3, t + 5)
            MSTEP((au + 128) ^ swz, pc0, pc1, pc2, pc3)
            if (tt + 6 < 8) LDB(pc0, pc1, pc2, pc3, t + 6)
            MSTEP((au + 192) ^ swz, pd0, pd1, pd2, pd3)
            if (tt + 7 < 8) LDB(pd0, pd1, pd2, pd3, t + 7)
            au += 256;
        }
    }
#undef LDB
#undef MSTEP

    // epilogue: C[m = quad*4+reg][n = lane&15] per 16x16 tile (m89 layout)
    const int rbase = (lane >> 4) * 4;
    const int ncol  = lane & 15;
    if constexpr (BUN == 2) {
        // fp32 LDS C-tile -> per-(row,bundle) Q^T transform -> d_out direct
        __syncthreads();                // all waves done reading Alds
        float* Cl = (float*)Alds;
        constexpr int CS4 = NOUT + 8;
#pragma unroll
        for (int nt = 0; nt < 4; nt++) {
            const int n = wave * 64 + nt * 16 + ncol;
            const float bs = bias[n];
#pragma unroll
            for (int mt = 0; mt < 4; mt++)
#pragma unroll
                for (int i = 0; i < 4; i++)
                    Cl[(mt * 16 + rbase + i) * CS4 + n] = acc[mt][nt][i] + bs;
        }
        __syncthreads();
#pragma unroll
        for (int it = 0; it < 4096 / NOUT; it++) {
            const int item = tid + it * NOUT;
            const int row = item >> 6, b = item & 63;
            float4 v = *(const float4*)&Cl[row * CS4 + b * 4];
            float Q[4][4];
            make_Q(nrq + (size_t)(m0 + row) * 384 + b * 6, Q);
            float4 o;
            o.x = Q[0][0]*v.x + Q[1][0]*v.y + Q[2][0]*v.z + Q[3][0]*v.w;
            o.y = Q[0][1]*v.x + Q[1][1]*v.y + Q[2][1]*v.z + Q[3][1]*v.w;
            o.z = Q[0][2]*v.x + Q[1][2]*v.y + Q[2][2]*v.z + Q[3][2]*v.w;
            o.w = Q[0][3]*v.x + Q[1][3]*v.y + Q[2][3]*v.z + Q[3][3]*v.w;
            *(float4*)(outf + (size_t)(m0 + row) * 256 + b * 4) = o;
        }
    } else {
        // W16: coalesced path via padded fp16 LDS C-tile
        __syncthreads();                // all waves done reading Alds
        constexpr int CPRN = NOUT / 8;  // 16B chunks per C row
        constexpr int CPT  = 64 * CPRN / NOUT;   // chunks per thread (= 8)
        f16x8 res[CPT];
        if constexpr (RESA) {
#pragma unroll
            for (int k2 = 0; k2 < CPT; k2++) {
                const int c = tid + k2 * NOUT;
                const int row = c / CPRN, col = c - row * CPRN;
                res[k2] = *(const f16x8*)(A1 + (size_t)(m0 + row) * 256 + col * 8);
            }
        }
#pragma unroll
        for (int nt = 0; nt < 4; nt++) {
            const int n = wave * 64 + nt * 16 + ncol;
            const float bs = bias[n];
#pragma unroll
            for (int mt = 0; mt < 4; mt++) {
#pragma unroll
                for (int i = 0; i < 4; i++) {
                    const int mr = mt * 16 + rbase + i;
                    float v = acc[mt][nt][i] + bs;
                    if (ACT) v = gelu_f(v);
                    Alds[mr * CTS + n] = (_Float16)v;
                }
            }
        }
        __syncthreads();
#pragma unroll
        for (int k2 = 0; k2 < CPT; k2++) {
            const int c = tid + k2 * NOUT;
            const int row = c / CPRN, col = c - row * CPRN;
            f16x8 v = *(const f16x8*)&Alds[row * CTS + col * 8];
            if constexpr (RESA) v = v + res[k2];
            *(f16x8*)(C16 + (size_t)(m0 + row) * NOUT + col * 8) = v;
        }
        if constexpr (BUN == 1) {
            // fused bundle<false>: vf16[n, b*4+i] = sum_j Q[i][j] x[n, b*4+j]
            constexpr int NIT = (4096 + NOUT - 1) / NOUT;
#pragma unroll
            for (int it = 0; it < NIT; it++) {
                const int item = tid + it * NOUT;
                if (item < 4096) {
                    const int row = item >> 6, b = item & 63;
                    float4 xv = *(const float4*)(xin + (size_t)(m0 + row) * 256 + b * 4);
                    float Q[4][4];
                    make_Q(&Alds[row * CTS + b * 6], Q);
                    f16x4 o = {
                        (_Float16)(Q[0][0]*xv.x + Q[0][1]*xv.y + Q[0][2]*xv.z + Q[0][3]*xv.w),
                        (_Float16)(Q[1][0]*xv.x + Q[1][1]*xv.y + Q[1][2]*xv.z + Q[1][3]*xv.w),
                        (_Float16)(Q[2][0]*xv.x + Q[2][1]*xv.y + Q[2][2]*xv.z + Q[2][3]*xv.w),
                        (_Float16)(Q[3][0]*xv.x + Q[3][1]*xv.y + Q[3][2]*xv.z + Q[3][3]*xv.w) };
                    *(f16x4*)(vf16 + (size_t)(m0 + row) * 256 + b * 4) = o;
                }
            }
        }
    }
}

// ---------------------------------------------------------------------------
// Merged prep kernel: 5 weight packs + bias combine + deg zero + hs zero in
// ONE launch (R10: cut 8 launches -> 1; each launch gap ~2-4us).
// Pack layout (chunk cid, runtime NOUT/lognt): value[j] =
//   W[t*32 + (l>>4)*8 + j][wn*64 + q*16 + (l&15)], k>=256 -> W2.
// Block ranges: [0,32) enc | [32,96) l1 | [96,160) l2 | [160,208) dec |
// [208,240) lin | 240 bcomb | [241,305) deg zero | [305,337) hs zero.
// ---------------------------------------------------------------------------
__device__ __forceinline__ void pack_body(
    const float* __restrict__ W1, const float* __restrict__ W2,
    _Float16* __restrict__ Bp, int cid, int NOUT, int lognt)
{
    const int NT = 1 << lognt;
    const int l  = cid & 63;
    const int q  = (cid >> 6) & 3;
    const int c2 = cid >> 8;            // wn*NT + t
    const int t  = c2 & (NT - 1);
    const int wn = c2 >> lognt;
    const int n  = wn * 64 + q * 16 + (l & 15);
    const int k0 = t * 32 + (l >> 4) * 8;
    f16x8 v;
#pragma unroll
    for (int j = 0; j < 8; j++) {
        const int k = k0 + j;
        float w = (W2 && k >= 256) ? W2[(size_t)(k - 256) * NOUT + n]
                                   : W1[(size_t)k * NOUT + n];
        v[j] = (_Float16)w;
    }
    *(f16x8*)(Bp + (size_t)cid * 8) = v;
}

__global__ __launch_bounds__(256) void packall_k(
    const float* __restrict__ enc_w, const float* __restrict__ self_w,
    const float* __restrict__ nb_w, const float* __restrict__ dec_w,
    const float* __restrict__ lin_w, const float* __restrict__ self_b,
    const float* __restrict__ nb_b,
    _Float16* __restrict__ enc16, _Float16* __restrict__ l1w,
    _Float16* __restrict__ l2w, _Float16* __restrict__ dec16,
    _Float16* __restrict__ lin16, float* __restrict__ lbias,
    float* __restrict__ degf, float* __restrict__ hs)
{
    const int b = blockIdx.x;
    const int tid = threadIdx.x;
    if (b < 32) {
        pack_body(enc_w, nullptr, enc16, b * 256 + tid, 256, 3);
    } else if (b < 96) {
        pack_body(self_w, nb_w, l1w, (b - 32) * 256 + tid, 256, 4);
    } else if (b < 160) {
        pack_body(self_w + 65536, nb_w + 65536, l2w, (b - 96) * 256 + tid, 256, 4);
    } else if (b < 208) {
        pack_body(dec_w, nullptr, dec16, (b - 160) * 256 + tid, 384, 3);
    } else if (b < 240) {
        pack_body(lin_w, nullptr, lin16, (b - 208) * 256 + tid, 256, 3);
    } else if (b == 240) {
        for (int i = tid; i < 512; i += 256) lbias[i] = self_b[i] + nb_b[i];
    } else if (b < 305) {
        // zero deg: 65536 ints = 16384 float4s
        const int j = (b - 241) * 256 + tid;
        ((float4*)degf)[j] = make_float4(0.f, 0.f, 0.f, 0.f);
    } else {
        // zero hs: 524288 floats = 131072 float4s, 8192 threads grid-stride
        for (int j = (b - 305) * 256 + tid; j < 131072; j += 8192)
            ((float4*)hs)[j] = make_float4(0.f, 0.f, 0.f, 0.f);
    }
}

// ---------------------------------------------------------------------------
// CSR build: histogram of dst, exclusive scan, cursor fill
// ---------------------------------------------------------------------------
__global__ __launch_bounds__(256) void hist_k(const int* __restrict__ ei, int* __restrict__ deg)
{
    int e = blockIdx.x * 256 + threadIdx.x;
    if (e < NEDGE) atomicAdd(&deg[ei[NEDGE + e]], 1);
}

__global__ __launch_bounds__(1024) void scan_k(
    const int* __restrict__ deg, int* __restrict__ off, int* __restrict__ cursor)
{
    __shared__ int sh[1024];
    const int tid = threadIdx.x;
    const int base = tid * 64;
    int s = 0;
#pragma unroll 8
    for (int i = 0; i < 64; i++) s += deg[base + i];
    const int mysum = s;
    sh[tid] = s;
    __syncthreads();
    for (int ofs = 1; ofs < 1024; ofs <<= 1) {
        int v = (tid >= ofs) ? sh[tid - ofs] : 0;
        __syncthreads();
        sh[tid] += v;
        __syncthreads();
    }
    int running = sh[tid] - mysum;
    for (int i = 0; i < 64; i++) {
        off[base + i] = running;
        cursor[base + i] = running;
        running += deg[base + i];
    }
    if (tid == 1023) off[NN] = running;
}

__global__ __launch_bounds__(256) void fill_k(
    const int* __restrict__ ei, int* __restrict__ cursor, int* __restrict__ csr)
{
    int e = blockIdx.x * 256 + threadIdx.x;
    if (e < NEDGE) {
        int d = ei[NEDGE + e];
        int pos = atomicAdd(&cursor[d], 1);
        csr[pos] = ei[e];   // src
    }
}

// ---------------------------------------------------------------------------
// Gather segment-sum over fp16 h: fp32 accum, fp16 out. 4 rows in flight.
// ---------------------------------------------------------------------------
__global__ __launch_bounds__(256) void gather16_k(
    const _Float16* __restrict__ h, const int* __restrict__ off,
    const int* __restrict__ csr, _Float16* __restrict__ agg)
{
    const int lane = threadIdx.x & 63;
    const int n = blockIdx.x * 4 + (threadIdx.x >> 6);
    const int s0 = off[n], s1 = off[n + 1];
    float a0 = 0.f, a1 = 0.f, a2 = 0.f, a3 = 0.f;
    int j = s0;
    for (; j + 3 < s1; j += 4) {
        const int i0 = csr[j], i1 = csr[j + 1], i2 = csr[j + 2], i3 = csr[j + 3];
        f16x4 v0 = ((const f16x4*)(h + (size_t)i0 * CH))[lane];
        f16x4 v1 = ((const f16x4*)(h + (size_t)i1 * CH))[lane];
        f16x4 v2 = ((const f16x4*)(h + (size_t)i2 * CH))[lane];
        f16x4 v3 = ((const f16x4*)(h + (size_t)i3 * CH))[lane];
        a0 += (float)v0[0] + (float)v1[0] + (float)v2[0] + (float)v3[0];
        a1 += (float)v0[1] + (float)v1[1] + (float)v2[1] + (float)v3[1];
        a2 += (float)v0[2] + (float)v1[2] + (float)v2[2] + (float)v3[2];
        a3 += (float)v0[3] + (float)v1[3] + (float)v2[3] + (float)v3[3];
    }
    for (; j < s1; j++) {
        f16x4 va = ((const f16x4*)(h + (size_t)csr[j] * CH))[lane];
        a0 += (float)va[0]; a1 += (float)va[1]; a2 += (float)va[2]; a3 += (float)va[3];
    }
    f16x4 o = { (_Float16)a0, (_Float16)a1, (_Float16)a2, (_Float16)a3 };
    ((f16x4*)(agg + (size_t)n * CH))[lane] = o;
}

// ---------------------------------------------------------------------------
// Spectral kernels (vf is fp16)
// ---------------------------------------------------------------------------
__global__ __launch_bounds__(256) void spec_proj_k(
    const _Float16* __restrict__ v, const float* __restrict__ eigvec, float* __restrict__ hs)
{
    const int g = blockIdx.x;
    const int nbase = g * NPG + blockIdx.y * 128;
    __shared__ float evs[16][32];
    float acc[32];
#pragma unroll
    for (int k = 0; k < 32; k++) acc[k] = 0.f;
    for (int nt = 0; nt < 128; nt += 16) {
        __syncthreads();
        for (int i = threadIdx.x; i < 512; i += 256) {
            int nn = i >> 5, kk = i & 31;
            evs[nn][kk] = eigvec[(size_t)(nbase + nt + nn) * KEIG + kk];
        }
        __syncthreads();
#pragma unroll 4
        for (int nn = 0; nn < 16; nn++) {
            float hv = (float)v[(size_t)(nbase + nt + nn) * CH + threadIdx.x];
#pragma unroll
            for (int k = 0; k < 32; k++) acc[k] += evs[nn][k] * hv;
        }
    }
    float* o = hs + (size_t)g * KEIG * CH + threadIdx.x;
#pragma unroll
    for (int k = 0; k < 32; k++) atomicAdd(o + k * CH, acc[k]);
}

// out16[g,n,d] = sum_v ev[g,n,v] * hs[g,v,d] * exp(-eigval[g,v]*taus[d>>2])
__global__ __launch_bounds__(256) void spec_reproj16_k(
    const float* __restrict__ eigvec, const float* __restrict__ hs,
    const float* __restrict__ eigval, const float* __restrict__ taus,
    _Float16* __restrict__ out16)
{
    const int g = blockIdx.x >> 4;
    const int nbase = g * NPG + (blockIdx.x & 15) * 64;
    const float tau = taus[threadIdx.x >> 2];
    float hsr[32];
    const float* hg = hs + (size_t)g * KEIG * CH + threadIdx.x;
#pragma unroll
    for (int k = 0; k < 32; k++)
        hsr[k] = hg[k * CH] * expf(-eigval[g * KEIG + k] * tau);
    __shared__ float evs[64][32];
    for (int i = threadIdx.x; i < 2048; i += 256) {
        int nn = i >> 5, kk = i & 31;
        evs[nn][kk] = eigvec[(size_t)(nbase + nn) * KEIG + kk];
    }
    __syncthreads();
    for (int nn = 0; nn < 64; nn++) {
        float a = 0.f;
#pragma unroll
        for (int k = 0; k < 32; k++) a += evs[nn][k] * hsr[k];
        out16[(size_t)(nbase + nn) * CH + threadIdx.x] = (_Float16)a;
    }
}

// ---------------------------------------------------------------------------
extern "C" void kernel_launch(void* const* d_in, const int* in_sizes, int n_in,
                              void* d_out, int out_size, void* d_ws, size_t ws_size,
                              hipStream_t stream)
{
    const float* x      = (const float*)d_in[0];
    const float* eigvec = (const float*)d_in[1];
    const float* eigval = (const float*)d_in[2];
    const float* taus   = (const float*)d_in[3];
    const float* enc_w  = (const float*)d_in[4];
    const float* enc_b  = (const float*)d_in[5];
    const float* self_w = (const float*)d_in[6];
    const float* self_b = (const float*)d_in[7];
    const float* nb_w   = (const float*)d_in[8];
    const float* nb_b   = (const float*)d_in[9];
    const float* dec_w  = (const float*)d_in[10];
    const float* dec_b  = (const float*)d_in[11];
    const float* lin_w  = (const float*)d_in[12];
    const float* lin_b  = (const float*)d_in[13];
    const int*   ei     = (const int*)d_in[14];
    (void)in_sizes; (void)n_in; (void)out_size; (void)ws_size;

    float* ws = (float*)d_ws;
    // Stream-ordered lifetimes (float-slot offsets):
    //  [0,        524288)   hs [64,32,256] fp32
    //  [8388608, 16777216)  h0
    //  [16777216,25165824)  h1 -> vf16 [NN,256] fp16 (h1 dead after L2)
    //  [25165824,33554432)  agg          -> nr16 part
    //  [33554432,34275329)  CSR ints     -> nr16 part
    //  [25165824,37748736)  nr16 [NN,384] fp16 (dec out; agg+CSR dead)
    //  [37748752,37995024)  packed weights + lbias
    //  [37995024,46383632)  h2 [NN,256] fp16
    // high-water: 46,383,632 fl = 185.5 MB
    _Float16* h0  = (_Float16*)(ws + 8388608);
    _Float16* h1  = (_Float16*)(ws + 16777216);
    _Float16* agg = (_Float16*)(ws + 25165824);
    int* ibase  = (int*)(ws + 33554432);
    int* deg    = ibase;                 // NN
    int* off    = ibase + 65536;         // NN+1
    int* cursor = ibase + 131073;        // NN
    int* csr    = ibase + 196609;        // NEDGE (ends slot 34275329)
    _Float16* nr16 = (_Float16*)(ws + 25165824);  // [NN,384] fp16
    float* wb = ws + 37748752;
    _Float16* enc16 = (_Float16*)(wb);            // packed [256x256]
    _Float16* l1w   = (_Float16*)(wb + 32768);    // packed [256x512]
    _Float16* l2w   = (_Float16*)(wb + 98304);    // packed [256x512]
    _Float16* dec16 = (_Float16*)(wb + 163840);   // packed [384x256]
    _Float16* lin16 = (_Float16*)(wb + 212992);   // packed [256x256]
    float* lbias = wb + 245760;                   // [2,256] (ends wb+246272)
    _Float16* h2 = (_Float16*)(ws + 37995024);    // [NN,256] fp16
    _Float16* vf16 = (_Float16*)(ws + 16777216);  // [NN,256] fp16 (h1 dead)
    float* hs  = ws;                              // [64,32,256] fp32

    dim3 blk(256);

    // ---- prep: packs + bias + zeros in ONE launch ----
    packall_k<<<337, blk, 0, stream>>>(enc_w, self_w, nb_w, dec_w, lin_w,
        self_b, nb_b, enc16, l1w, l2w, dec16, lin16, lbias, (float*)deg, hs);
    hist_k<<<NEDGE / 256, blk, 0, stream>>>(ei, deg);
    scan_k<<<1, 1024, 0, stream>>>(deg, off, cursor);
    fill_k<<<NEDGE / 256, blk, 0, stream>>>(ei, cursor, csr);

    // ---- h0 = gelu(x @ enc_w + enc_b)  (A32: stages fp32 x directly) ----
    mgemm_k<256, 256, false, true, false, true, true, 0><<<1024, blk, 0, stream>>>(
        nullptr, nullptr, x, enc16, enc_b, h0, nullptr, nullptr, nullptr, nullptr);

    // ---- GNN layer 1: h1 = gelu([h0,agg]@W + b) + h0 ----
    gather16_k<<<NN / 4, blk, 0, stream>>>(h0, off, csr, agg);
    mgemm_k<256, 512, true, true, true, true, false, 0><<<1024, blk, 0, stream>>>(
        h0, agg, nullptr, l1w, lbias, h1, nullptr, nullptr, nullptr, nullptr);

    // ---- GNN layer 2: h0 = gelu([h1,agg]@W + b) + h1 ----
    gather16_k<<<NN / 4, blk, 0, stream>>>(h1, off, csr, agg);
    mgemm_k<256, 512, true, true, true, true, false, 0><<<1024, blk, 0, stream>>>(
        h1, agg, nullptr, l2w, lbias + 256, h0, nullptr, nullptr, nullptr, nullptr);

    // ---- node_rep = h0 @ dec_w + dec_b  + FUSED vf16 = Q . x ----
    mgemm_k<384, 256, false, false, false, true, false, 1><<<1024, dim3(384), 0, stream>>>(
        h0, nullptr, nullptr, dec16, dec_b, nr16, x, vf16, nullptr, nullptr);

    // ---- spectral filter (hs pre-zeroed in packall; scale fused in reproj) --
    spec_proj_k<<<dim3(GG, 8), blk, 0, stream>>>(vf16, eigvec, hs);
    spec_reproj16_k<<<GG * 16, blk, 0, stream>>>(eigvec, hs, eigval, taus, h2);

    // ---- out = Q^T . (h2 @ lin_w + lin_b)  (FUSED, fp32 tile, direct) ----
    mgemm_k<256, 256, false, false, false, false, false, 2><<<1024, blk, 0, stream>>>(
        h2, nullptr, nullptr, lin16, lin_b, nullptr, nullptr, nullptr, nr16, (float*)d_out);
}